// Round 1
// baseline (426.537 us; speedup 1.0000x reference)
//
#include <hip/hip_runtime.h>
#include <math.h>

#define N_NODES 384
#define N_EDGES 1280

// ---------------------------------------------------------------------------
// prep: recover snd/rcv indices from one-hot Ro/Ri, compute H0 = [2pi*sig(XW), X]
// ---------------------------------------------------------------------------
__global__ void prep_kernel(const float* __restrict__ X, const float* __restrict__ Ri,
                            const float* __restrict__ Ro, const float* __restrict__ W,
                            int* __restrict__ snd, int* __restrict__ rcv,
                            float* __restrict__ H0)
{
    int tid = blockIdx.x * blockDim.x + threadIdx.x;
    if (tid < N_EDGES) {
        int s_ = 0, r_ = 0;
        for (int n = 0; n < N_NODES; n++) {
            if (Ro[n * N_EDGES + tid] > 0.5f) s_ = n;
            if (Ri[n * N_EDGES + tid] > 0.5f) r_ = n;
        }
        snd[tid] = s_;
        rcv[tid] = r_;
    } else if (tid < N_EDGES + N_NODES) {
        int n = tid - N_EDGES;
        float x0 = X[n * 3 + 0], x1 = X[n * 3 + 1], x2 = X[n * 3 + 2];
        float t0 = x0 * W[0] + x1 * W[2] + x2 * W[4];
        float t1 = x0 * W[1] + x1 * W[3] + x2 * W[5];
        const float TP = 6.2831853071795864769f;
        H0[n * 5 + 0] = TP / (1.f + expf(-t0));
        H0[n * 5 + 1] = TP / (1.f + expf(-t1));
        H0[n * 5 + 2] = x0;
        H0[n * 5 + 3] = x1;
        H0[n * 5 + 4] = x2;
    }
}

// ---------------------------------------------------------------------------
// edge circuit: 10 qubits, 1024 amps, one wave (64 lanes) per edge,
// 16 amps per lane in registers. amp index i = lane*16 + r.
// bit b of i (b = 9 - wire): b in [4,9] -> lane bit (b-4); b in [0,3] -> r bit.
// ---------------------------------------------------------------------------
template <int WIRE>
__device__ __forceinline__ void ry10(float (&amp)[16], int lane, float c_, float s_)
{
    constexpr int B = 9 - WIRE;
    if constexpr (B >= 4) {
        constexpr int LM = 1 << (B - 4);
        const int mybit = (lane >> (B - 4)) & 1;
#pragma unroll
        for (int r = 0; r < 16; r++) {
            float other = __shfl_xor(amp[r], LM, 64);
            float v0 = c_ * amp[r] - s_ * other;   // if my bit == 0
            float v1 = s_ * other + c_ * amp[r];   // if my bit == 1
            amp[r] = mybit ? v1 : v0;
        }
    } else {
        constexpr int M = 1 << B;
#pragma unroll
        for (int r = 0; r < 16; r++) {
            if ((r & M) == 0) {
                float a = amp[r], b = amp[r | M];
                amp[r]     = c_ * a - s_ * b;
                amp[r | M] = s_ * a + c_ * b;
            }
        }
    }
}

template <int CW, int TW>
__device__ __forceinline__ void cx10(float (&amp)[16], int lane)
{
    constexpr int BC = 9 - CW;
    constexpr int BT = 9 - TW;
    if constexpr (BC >= 4 && BT >= 4) {
        constexpr int LM = 1 << (BT - 4);
        const int ctrl = (lane >> (BC - 4)) & 1;
#pragma unroll
        for (int r = 0; r < 16; r++) {
            float other = __shfl_xor(amp[r], LM, 64);
            amp[r] = ctrl ? other : amp[r];
        }
    } else if constexpr (BC >= 4 && BT < 4) {
        constexpr int M = 1 << BT;
        const int ctrl = (lane >> (BC - 4)) & 1;
#pragma unroll
        for (int r = 0; r < 16; r++) {
            if ((r & M) == 0) {
                float a = amp[r], b = amp[r | M];
                amp[r]     = ctrl ? b : a;
                amp[r | M] = ctrl ? a : b;
            }
        }
    } else if constexpr (BC < 4 && BT >= 4) {
        constexpr int LM = 1 << (BT - 4);
#pragma unroll
        for (int r = 0; r < 16; r++) {
            float other = __shfl_xor(amp[r], LM, 64);
            if (r & (1 << BC)) amp[r] = other;
        }
    } else {
        constexpr int MC = 1 << BC, MT = 1 << BT;
#pragma unroll
        for (int r = 0; r < 16; r++) {
            if ((r & MC) && !(r & MT)) {
                float t = amp[r]; amp[r] = amp[r | MT]; amp[r | MT] = t;
            }
        }
    }
}

__global__ __launch_bounds__(64) void edge_kernel(
    const float* __restrict__ H, const int* __restrict__ snd, const int* __restrict__ rcv,
    const float* __restrict__ th, float* __restrict__ out)
{
    const int e = blockIdx.x;
    const int lane = threadIdx.x;

    // feats: [H[snd] (wires 0-4), H[rcv] (wires 5-9)]
    float f[10];
    const float* hs = H + snd[e] * 5;
    const float* hr = H + rcv[e] * 5;
#pragma unroll
    for (int k = 0; k < 5; k++) { f[k] = hs[k]; f[5 + k] = hr[k]; }

    float cw[10], sw[10];
#pragma unroll
    for (int w = 0; w < 10; w++) {
        float h = 0.5f * f[w];
        sw[w] = sinf(h);
        cw[w] = cosf(h);
    }

    // product state: amp[i], i = lane*16 + r. bit b <-> wire 9-b.
    float plane = 1.f;
#pragma unroll
    for (int lb = 0; lb < 6; lb++) {                 // lane bit lb = global bit lb+4, wire 5-lb
        int bit = (lane >> lb) & 1;
        plane *= bit ? sw[5 - lb] : cw[5 - lb];
    }
    float amp[16];
#pragma unroll
    for (int r = 0; r < 16; r++) {
        float p = plane;
#pragma unroll
        for (int bb = 0; bb < 4; bb++) {             // r bit bb = global bit bb, wire 9-bb
            int bit = (r >> bb) & 1;
            p *= bit ? sw[9 - bb] : cw[9 - bb];
        }
        amp[r] = p;
    }

#define ERY(WI, IDX) { float h_ = 0.5f * th[IDX]; float s_ = sinf(h_), c_ = cosf(h_); ry10<WI>(amp, lane, c_, s_); }
    // EDGE_OPS
    ERY(0, 0)  ERY(1, 1)  cx10<0, 1>(amp, lane);
    ERY(2, 2)  ERY(3, 3)  cx10<3, 2>(amp, lane);
    ERY(4, 4)  ERY(5, 5)  cx10<5, 4>(amp, lane);
    ERY(6, 6)  ERY(7, 7)  cx10<6, 7>(amp, lane);
    ERY(8, 8)  ERY(9, 9)  cx10<8, 9>(amp, lane);
    ERY(1, 10) ERY(2, 11) cx10<1, 2>(amp, lane);
    ERY(7, 12) ERY(9, 13) cx10<9, 7>(amp, lane);
    ERY(2, 14) ERY(4, 15) cx10<2, 4>(amp, lane);
    ERY(4, 16) ERY(7, 17) cx10<4, 7>(amp, lane);
    ERY(7, 18)
#undef ERY

    // expz on wire 7 -> bit b=2 (an r bit)
    float z = 0.f;
#pragma unroll
    for (int r = 0; r < 16; r++) {
        float v = amp[r] * amp[r];
        z += (r & 4) ? -v : v;
    }
#pragma unroll
    for (int o = 32; o > 0; o >>= 1) z += __shfl_xor(z, o, 64);
    if (lane == 0) out[e] = 0.5f * (1.f - z);
}

// ---------------------------------------------------------------------------
// node circuit: 15 qubits, 32768 amps in (dynamic) LDS, 512 threads/block.
// ---------------------------------------------------------------------------
__device__ __forceinline__ void ry15(float* sh, int b, float c_, float s_, int tid)
{
    const int m = 1 << b;
    for (int p = tid; p < 16384; p += 512) {
        int i0 = ((p >> b) << (b + 1)) | (p & (m - 1));
        int i1 = i0 | m;
        float a = sh[i0], bb = sh[i1];
        sh[i0] = c_ * a - s_ * bb;
        sh[i1] = s_ * a + c_ * bb;
    }
    __syncthreads();
}

__device__ __forceinline__ void cx15(float* sh, int bc, int bt, int tid)
{
    const int bl = bc < bt ? bc : bt;
    const int bh = bc < bt ? bt : bc;
    const int ml = (1 << bl) - 1;
    const int mh = (1 << bh) - 1;
    for (int p = tid; p < 8192; p += 512) {
        int q = ((p >> bl) << (bl + 1)) | (p & ml);
        int i = ((q >> bh) << (bh + 1)) | (q & mh);
        i |= (1 << bc);                 // control bit = 1, target bit = 0
        int i1 = i | (1 << bt);
        float a = sh[i], b2 = sh[i1];
        sh[i] = b2;
        sh[i1] = a;
    }
    __syncthreads();
}

__global__ __launch_bounds__(512) void node_kernel(
    const float* __restrict__ H, const float* __restrict__ ev,
    const int* __restrict__ snd, const int* __restrict__ rcv,
    const float* __restrict__ th, const float* __restrict__ X,
    float* __restrict__ Hout)
{
    extern __shared__ float sh[];               // 32768 floats = 128 KiB
    const int n = blockIdx.x;
    const int tid = threadIdx.x;

    __shared__ float acc[10];                   // mi[0..4], mo[5..9]
    __shared__ float cw[15], sw[15];            // feat half-angle cos/sin
    __shared__ float ctt[31], stt[31];          // theta half-angle cos/sin
    __shared__ float red[16];

    if (tid < 10) acc[tid] = 0.f;
    __syncthreads();

    // mi[n] = sum_{e: rcv[e]==n} ev[e]*H[snd[e]];  mo[n] = sum_{e: snd[e]==n} ev[e]*H[rcv[e]]
    for (int e = tid; e < N_EDGES; e += 512) {
        int se = snd[e], re = rcv[e];
        float w = ev[e];
        if (re == n) {
#pragma unroll
            for (int k = 0; k < 5; k++) atomicAdd(&acc[k], w * H[se * 5 + k]);
        }
        if (se == n) {
#pragma unroll
            for (int k = 0; k < 5; k++) atomicAdd(&acc[5 + k], w * H[re * 5 + k]);
        }
    }
    __syncthreads();

    if (tid < 15) {
        float ang = (tid < 10) ? acc[tid] : H[n * 5 + (tid - 10)];
        float h = 0.5f * ang;
        sw[tid] = sinf(h);
        cw[tid] = cosf(h);
    }
    if (tid >= 32 && tid < 63) {
        int j = tid - 32;
        float h = 0.5f * th[j];
        stt[j] = sinf(h);
        ctt[j] = cosf(h);
    }
    __syncthreads();

    // product state: i = r*512 + tid ; bit b <-> wire 14-b.
    float plow = 1.f;
#pragma unroll
    for (int b = 0; b < 9; b++) plow *= ((tid >> b) & 1) ? sw[14 - b] : cw[14 - b];
    float pa[8], pb[8];
#pragma unroll
    for (int q = 0; q < 8; q++) {
        float v = 1.f, u = 1.f;
#pragma unroll
        for (int j = 0; j < 3; j++) {
            int bit = (q >> j) & 1;
            v *= bit ? sw[14 - (9 + j)]  : cw[14 - (9 + j)];   // bits 9..11 -> wires 5..3
            u *= bit ? sw[14 - (12 + j)] : cw[14 - (12 + j)];  // bits 12..14 -> wires 2..0
        }
        pa[q] = v;
        pb[q] = u;
    }
#pragma unroll
    for (int r = 0; r < 64; r++) sh[(r << 9) + tid] = plow * pa[r & 7] * pb[r >> 3];
    __syncthreads();

#define NRY(B, IDX) ry15(sh, B, ctt[IDX], stt[IDX], tid);
    // NODE_OPS (b = 14 - wire)
    NRY(14, 0)  NRY(13, 1)  cx15(sh, 14, 13, tid);
    NRY(12, 2)  NRY(11, 3)  cx15(sh, 11, 12, tid);
    NRY(10, 4)  NRY(9, 5)   cx15(sh, 10, 9, tid);
    NRY(8, 6)   NRY(7, 7)   cx15(sh, 7, 8, tid);
    NRY(6, 8)   NRY(5, 9)   cx15(sh, 6, 5, tid);
    NRY(4, 10)  NRY(3, 11)  cx15(sh, 3, 4, tid);
    NRY(2, 12)  NRY(1, 13)  cx15(sh, 6, 5, tid);
    NRY(0, 14)
    NRY(13, 15) NRY(12, 16) cx15(sh, 13, 12, tid);
    NRY(9, 14)  NRY(8, 15)  cx15(sh, 8, 9, tid);
    NRY(5, 16)  NRY(4, 17)  cx15(sh, 5, 4, tid);
    NRY(1, 18)  NRY(0, 19)  cx15(sh, 5, 4, tid);
    NRY(12, 19) NRY(9, 20)  cx15(sh, 12, 9, tid);
    NRY(4, 21)  NRY(1, 22)  cx15(sh, 1, 4, tid);
    NRY(9, 23)  NRY(4, 24)
    NRY(14, 25) NRY(9, 26)  cx15(sh, 14, 9, tid);
    NRY(4, 27)  NRY(0, 28)  cx15(sh, 0, 4, tid);
    NRY(9, 29)  NRY(4, 30)
#undef NRY

    // expz wires 5 (bit 9) and 10 (bit 4)
    float z5 = 0.f, z10 = 0.f;
    for (int i = tid; i < 32768; i += 512) {
        float v = sh[i];
        v *= v;
        z5  += (i & (1 << 9)) ? -v : v;
        z10 += (i & (1 << 4)) ? -v : v;
    }
#pragma unroll
    for (int o = 32; o > 0; o >>= 1) {
        z5  += __shfl_xor(z5, o, 64);
        z10 += __shfl_xor(z10, o, 64);
    }
    const int wv = tid >> 6;
    if ((tid & 63) == 0) { red[wv] = z5; red[8 + wv] = z10; }
    __syncthreads();
    if (tid == 0) {
        float a5 = 0.f, a10 = 0.f;
#pragma unroll
        for (int k = 0; k < 8; k++) { a5 += red[k]; a10 += red[8 + k]; }
        const float PI_ = 3.14159265358979323846f;
        Hout[n * 5 + 0] = PI_ * (1.f - a5);
        Hout[n * 5 + 1] = PI_ * (1.f - a10);
        Hout[n * 5 + 2] = X[n * 3 + 0];
        Hout[n * 5 + 3] = X[n * 3 + 1];
        Hout[n * 5 + 4] = X[n * 3 + 2];
    }
}

// ---------------------------------------------------------------------------
extern "C" void kernel_launch(void* const* d_in, const int* in_sizes, int n_in,
                              void* d_out, int out_size, void* d_ws, size_t ws_size,
                              hipStream_t stream)
{
    const float* X    = (const float*)d_in[0];
    const float* Ri   = (const float*)d_in[1];
    const float* Ro   = (const float*)d_in[2];
    const float* W    = (const float*)d_in[3];
    const float* th_e = (const float*)d_in[4];
    const float* th_n = (const float*)d_in[5];
    float* out = (float*)d_out;

    float* Ha  = (float*)d_ws;          // 384*5
    float* Hb  = Ha + N_NODES * 5;      // 384*5
    float* ev  = Hb + N_NODES * 5;      // 1280
    int*   snd = (int*)(ev + N_EDGES);  // 1280
    int*   rcv = snd + N_EDGES;         // 1280

    // allow 128 KiB dynamic LDS for node_kernel (gfx950 has 160 KiB/CU)
    (void)hipFuncSetAttribute((const void*)node_kernel,
                              hipFuncAttributeMaxDynamicSharedMemorySize, 131072);

    prep_kernel<<<(N_EDGES + N_NODES + 255) / 256, 256, 0, stream>>>(X, Ri, Ro, W, snd, rcv, Ha);
    edge_kernel<<<N_EDGES, 64, 0, stream>>>(Ha, snd, rcv, th_e, ev);
    node_kernel<<<N_NODES, 512, 131072, stream>>>(Ha, ev, snd, rcv, th_n, X, Hb);
    edge_kernel<<<N_EDGES, 64, 0, stream>>>(Hb, snd, rcv, th_e, ev);
    node_kernel<<<N_NODES, 512, 131072, stream>>>(Hb, ev, snd, rcv, th_n, X, Ha);
    edge_kernel<<<N_EDGES, 64, 0, stream>>>(Ha, snd, rcv, th_e, out);
}

// Round 2
// 273.382 us; speedup vs baseline: 1.5602x; 1.5602x over previous
//
#include <hip/hip_runtime.h>
#include <math.h>

#define N_NODES 384
#define N_EDGES 1280

// ---------------------------------------------------------------------------
// prep: recover snd/rcv indices from one-hot Ro/Ri, compute H0 = [2pi*sig(XW), X]
// ---------------------------------------------------------------------------
__global__ void prep_kernel(const float* __restrict__ X, const float* __restrict__ Ri,
                            const float* __restrict__ Ro, const float* __restrict__ W,
                            int* __restrict__ snd, int* __restrict__ rcv,
                            float* __restrict__ H0)
{
    int tid = blockIdx.x * blockDim.x + threadIdx.x;
    if (tid < N_EDGES) {
        int s_ = 0, r_ = 0;
        for (int n = 0; n < N_NODES; n++) {
            if (Ro[n * N_EDGES + tid] > 0.5f) s_ = n;
            if (Ri[n * N_EDGES + tid] > 0.5f) r_ = n;
        }
        snd[tid] = s_;
        rcv[tid] = r_;
    } else if (tid < N_EDGES + N_NODES) {
        int n = tid - N_EDGES;
        float x0 = X[n * 3 + 0], x1 = X[n * 3 + 1], x2 = X[n * 3 + 2];
        float t0 = x0 * W[0] + x1 * W[2] + x2 * W[4];
        float t1 = x0 * W[1] + x1 * W[3] + x2 * W[5];
        const float TP = 6.2831853071795864769f;
        H0[n * 5 + 0] = TP / (1.f + expf(-t0));
        H0[n * 5 + 1] = TP / (1.f + expf(-t1));
        H0[n * 5 + 2] = x0;
        H0[n * 5 + 3] = x1;
        H0[n * 5 + 4] = x2;
    }
}

// ---------------------------------------------------------------------------
// edge circuit: 10 qubits, 1024 amps, one wave (64 lanes) per edge,
// 16 amps per lane in registers. amp index i = lane*16 + r.
// ---------------------------------------------------------------------------
template <int WIRE>
__device__ __forceinline__ void ry10(float (&amp)[16], int lane, float c_, float s_)
{
    constexpr int B = 9 - WIRE;
    if constexpr (B >= 4) {
        constexpr int LM = 1 << (B - 4);
        const int mybit = (lane >> (B - 4)) & 1;
#pragma unroll
        for (int r = 0; r < 16; r++) {
            float other = __shfl_xor(amp[r], LM, 64);
            float v0 = c_ * amp[r] - s_ * other;
            float v1 = s_ * other + c_ * amp[r];
            amp[r] = mybit ? v1 : v0;
        }
    } else {
        constexpr int M = 1 << B;
#pragma unroll
        for (int r = 0; r < 16; r++) {
            if ((r & M) == 0) {
                float a = amp[r], b = amp[r | M];
                amp[r]     = c_ * a - s_ * b;
                amp[r | M] = s_ * a + c_ * b;
            }
        }
    }
}

template <int CW, int TW>
__device__ __forceinline__ void cx10(float (&amp)[16], int lane)
{
    constexpr int BC = 9 - CW;
    constexpr int BT = 9 - TW;
    if constexpr (BC >= 4 && BT >= 4) {
        constexpr int LM = 1 << (BT - 4);
        const int ctrl = (lane >> (BC - 4)) & 1;
#pragma unroll
        for (int r = 0; r < 16; r++) {
            float other = __shfl_xor(amp[r], LM, 64);
            amp[r] = ctrl ? other : amp[r];
        }
    } else if constexpr (BC >= 4 && BT < 4) {
        constexpr int M = 1 << BT;
        const int ctrl = (lane >> (BC - 4)) & 1;
#pragma unroll
        for (int r = 0; r < 16; r++) {
            if ((r & M) == 0) {
                float a = amp[r], b = amp[r | M];
                amp[r]     = ctrl ? b : a;
                amp[r | M] = ctrl ? a : b;
            }
        }
    } else if constexpr (BC < 4 && BT >= 4) {
        constexpr int LM = 1 << (BT - 4);
#pragma unroll
        for (int r = 0; r < 16; r++) {
            float other = __shfl_xor(amp[r], LM, 64);
            if (r & (1 << BC)) amp[r] = other;
        }
    } else {
        constexpr int MC = 1 << BC, MT = 1 << BT;
#pragma unroll
        for (int r = 0; r < 16; r++) {
            if ((r & MC) && !(r & MT)) {
                float t = amp[r]; amp[r] = amp[r | MT]; amp[r | MT] = t;
            }
        }
    }
}

__global__ __launch_bounds__(64) void edge_kernel(
    const float* __restrict__ H, const int* __restrict__ snd, const int* __restrict__ rcv,
    const float* __restrict__ th, float* __restrict__ out)
{
    const int e = blockIdx.x;
    const int lane = threadIdx.x;

    float f[10];
    const float* hs = H + snd[e] * 5;
    const float* hr = H + rcv[e] * 5;
#pragma unroll
    for (int k = 0; k < 5; k++) { f[k] = hs[k]; f[5 + k] = hr[k]; }

    float cw[10], sw[10];
#pragma unroll
    for (int w = 0; w < 10; w++) {
        float h = 0.5f * f[w];
        sw[w] = sinf(h);
        cw[w] = cosf(h);
    }

    float plane = 1.f;
#pragma unroll
    for (int lb = 0; lb < 6; lb++) {
        int bit = (lane >> lb) & 1;
        plane *= bit ? sw[5 - lb] : cw[5 - lb];
    }
    float amp[16];
#pragma unroll
    for (int r = 0; r < 16; r++) {
        float p = plane;
#pragma unroll
        for (int bb = 0; bb < 4; bb++) {
            int bit = (r >> bb) & 1;
            p *= bit ? sw[9 - bb] : cw[9 - bb];
        }
        amp[r] = p;
    }

#define ERY(WI, IDX) { float h_ = 0.5f * th[IDX]; float s_ = sinf(h_), c_ = cosf(h_); ry10<WI>(amp, lane, c_, s_); }
    ERY(0, 0)  ERY(1, 1)  cx10<0, 1>(amp, lane);
    ERY(2, 2)  ERY(3, 3)  cx10<3, 2>(amp, lane);
    ERY(4, 4)  ERY(5, 5)  cx10<5, 4>(amp, lane);
    ERY(6, 6)  ERY(7, 7)  cx10<6, 7>(amp, lane);
    ERY(8, 8)  ERY(9, 9)  cx10<8, 9>(amp, lane);
    ERY(1, 10) ERY(2, 11) cx10<1, 2>(amp, lane);
    ERY(7, 12) ERY(9, 13) cx10<9, 7>(amp, lane);
    ERY(2, 14) ERY(4, 15) cx10<2, 4>(amp, lane);
    ERY(4, 16) ERY(7, 17) cx10<4, 7>(amp, lane);
    ERY(7, 18)
#undef ERY

    float z = 0.f;
#pragma unroll
    for (int r = 0; r < 16; r++) {
        float v = amp[r] * amp[r];
        z += (r & 4) ? -v : v;
    }
#pragma unroll
    for (int o = 32; o > 0; o >>= 1) z += __shfl_xor(z, o, 64);
    if (lane == 0) out[e] = 0.5f * (1.f - z);
}

// ---------------------------------------------------------------------------
// node circuit: 15 qubits, 32768 amps ALL IN REGISTERS across 1024 threads.
// amp index i = wave(4b, i[14:11]) | lane(6b, i[10:5]) | r(5b, i[4:0]).
// Logical bit lb (= 14 - wire) -> physical bit P[lb]:
//   P[4]=0 P[9]=1 P[12]=2 P[1]=3 P[0]=4          (register bits, 23 RYs)
//   P[14]=5 P[13]=6 P[8]=7 P[5]=8 P[2]=9 P[6]=10 (lane bits, 10 RYs)
//   P[11]=11 P[10]=12 P[7]=13 P[3]=14            (wave bits, 1 RY each, no CX tgt)
// Only the 4 wave-bit RYs need an LDS exchange (float4, XOR-swizzled).
// ---------------------------------------------------------------------------
template <int M>        // register-bit RY, M = 1<<pb (pb in 0..4)
__device__ __forceinline__ void ry_r(float (&a)[32], float c_, float s_)
{
#pragma unroll
    for (int r = 0; r < 32; r++) {
        if ((r & M) == 0) {
            float a0 = a[r], a1 = a[r | M];
            a[r]     = c_ * a0 - s_ * a1;
            a[r | M] = s_ * a0 + c_ * a1;
        }
    }
}

template <int LM>       // lane-bit RY, LM = 1<<(pb-5)
__device__ __forceinline__ void ry_l(float (&a)[32], int lane, float c_, float s_)
{
    const float ss = (lane & LM) ? s_ : -s_;
#pragma unroll
    for (int r = 0; r < 32; r++) {
        float o = __shfl_xor(a[r], LM, 64);
        a[r] = fmaf(ss, o, c_ * a[r]);
    }
}

template <int K>        // wave-bit RY, wave bit K (0..3): LDS exchange
__device__ __forceinline__ void ry_w(float (&a)[32], float* sh, int tid, float c_, float s_)
{
    float4* v4 = (float4*)sh;
    const int sw7  = tid & 7;            // XOR swizzle: spreads quads across banks
    const int base = tid * 8;
    __syncthreads();                     // prior exchange's reads complete
#pragma unroll
    for (int j = 0; j < 8; j++)
        v4[base + (j ^ sw7)] = make_float4(a[4*j], a[4*j+1], a[4*j+2], a[4*j+3]);
    __syncthreads();
    const int pbase = (tid ^ (64 << K)) * 8;
    const float ss = (tid & (64 << K)) ? s_ : -s_;
#pragma unroll
    for (int j = 0; j < 8; j++) {
        float4 o = v4[pbase + (j ^ sw7)];
        a[4*j+0] = fmaf(ss, o.x, c_ * a[4*j+0]);
        a[4*j+1] = fmaf(ss, o.y, c_ * a[4*j+1]);
        a[4*j+2] = fmaf(ss, o.z, c_ * a[4*j+2]);
        a[4*j+3] = fmaf(ss, o.w, c_ * a[4*j+3]);
    }
}

template <int TM>       // CX: ctrl = bool (wave- or lane-derived), target = register bit
__device__ __forceinline__ void cx_xr(float (&a)[32], bool ctrl)
{
#pragma unroll
    for (int r = 0; r < 32; r++) {
        if ((r & TM) == 0) {
            float a0 = a[r], a1 = a[r | TM];
            a[r]      = ctrl ? a1 : a0;
            a[r | TM] = ctrl ? a0 : a1;
        }
    }
}

template <int TM>       // CX: ctrl = bool, target = lane bit
__device__ __forceinline__ void cx_xl(float (&a)[32], bool ctrl)
{
#pragma unroll
    for (int r = 0; r < 32; r++) {
        float o = __shfl_xor(a[r], TM, 64);
        a[r] = ctrl ? o : a[r];
    }
}

template <int CM, int TM>  // CX: ctrl lane bit, target lane bit
__device__ __forceinline__ void cx_ll(float (&a)[32], int lane)
{
    const bool ctrl = (lane & CM) != 0;
#pragma unroll
    for (int r = 0; r < 32; r++) {
        float o = __shfl_xor(a[r], TM, 64);
        a[r] = ctrl ? o : a[r];
    }
}

template <int CM, int TM>  // CX: ctrl register bit, target register bit (pure rename)
__device__ __forceinline__ void cx_rr(float (&a)[32])
{
#pragma unroll
    for (int r = 0; r < 32; r++) {
        if ((r & CM) && !(r & TM)) {
            float t = a[r]; a[r] = a[r | TM]; a[r | TM] = t;
        }
    }
}

__global__ __launch_bounds__(1024) void node_kernel(
    const float* __restrict__ H, const float* __restrict__ ev,
    const int* __restrict__ snd, const int* __restrict__ rcv,
    const float* __restrict__ th, const float* __restrict__ X,
    float* __restrict__ Hout)
{
    extern __shared__ float sh[];               // 32768 floats (exchange buffer)
    const int n = blockIdx.x;
    const int tid = threadIdx.x;
    const int lane = tid & 63;
    const int wv = tid >> 6;

    __shared__ float acc[10];                   // mi[0..4], mo[5..9]
    __shared__ float cw[15], sw[15];            // indexed by PHYSICAL bit
    __shared__ float ct[31], st[31];
    __shared__ float red[32];

    if (tid < 10) acc[tid] = 0.f;
    __syncthreads();

    for (int e = tid; e < N_EDGES; e += 1024) {
        int se = snd[e], re = rcv[e];
        float w = ev[e];
        if (re == n) {
#pragma unroll
            for (int k = 0; k < 5; k++) atomicAdd(&acc[k], w * H[se * 5 + k]);
        }
        if (se == n) {
#pragma unroll
            for (int k = 0; k < 5; k++) atomicAdd(&acc[5 + k], w * H[re * 5 + k]);
        }
    }
    __syncthreads();

    if (tid < 15) {
        // physical bit -> wire
        const int wire_of_pb[15] = {10, 5, 2, 13, 14, 0, 1, 6, 9, 12, 8, 3, 4, 7, 11};
        int w_ = wire_of_pb[tid];
        float ang = (w_ < 10) ? acc[w_] : H[n * 5 + (w_ - 10)];
        float h = 0.5f * ang;
        sw[tid] = sinf(h);
        cw[tid] = cosf(h);
    }
    if (tid >= 32 && tid < 63) {
        int j = tid - 32;
        float h = 0.5f * th[j];
        st[j] = sinf(h);
        ct[j] = cosf(h);
    }
    __syncthreads();

    // product state
    float pw = 1.f;
#pragma unroll
    for (int k = 0; k < 6; k++) pw *= ((lane >> k) & 1) ? sw[5 + k] : cw[5 + k];
#pragma unroll
    for (int k = 0; k < 4; k++) pw *= ((wv >> k) & 1) ? sw[11 + k] : cw[11 + k];
    float a[32];
#pragma unroll
    for (int r = 0; r < 32; r++) {
        float p = pw;
#pragma unroll
        for (int j = 0; j < 5; j++) p *= ((r >> j) & 1) ? sw[j] : cw[j];
        a[r] = p;
    }

    const bool w0 = (wv & 1) != 0, w1 = (wv & 2) != 0, w2 = (wv & 4) != 0, w3 = (wv & 8) != 0;

#define RYR(PB, I) ry_r<(1 << PB)>(a, ct[I], st[I]);
#define RYL(K, I)  ry_l<(1 << K)>(a, lane, ct[I], st[I]);
#define RYW(K, I)  ry_w<K>(a, sh, tid, ct[I], st[I]);

    RYL(0, 0)   RYL(1, 1)   cx_ll<1, 2>(a, lane);            // ry w0, ry w1, cx(0,1)
    RYR(2, 2)   RYW(0, 3)   cx_xr<4>(a, w0);                 // ry w2, ry w3, cx(3,2)
    RYW(1, 4)   RYR(1, 5)   cx_xr<2>(a, w1);                 // ry w4, ry w5, cx(4,5)
    RYL(2, 6)   RYW(2, 7)   cx_xl<4>(a, w2);                 // ry w6, ry w7, cx(7,6)
    RYL(5, 8)   RYL(3, 9)   cx_ll<32, 8>(a, lane);           // ry w8, ry w9, cx(8,9)
    RYR(0, 10)  RYW(3, 11)  cx_xr<1>(a, w3);                 // ry w10, ry w11, cx(11,10)
    RYL(4, 12)  RYR(3, 13)  cx_ll<32, 8>(a, lane);           // ry w12, ry w13, cx(8,9)
    RYR(4, 14)                                               // ry w14
    RYL(1, 15)  RYR(2, 16)  cx_xr<4>(a, (lane & 2) != 0);    // ry w1, ry w2, cx(1,2)
    RYR(1, 14)  RYL(2, 15)  cx_xr<2>(a, (lane & 4) != 0);    // ry w5, ry w6, cx(6,5)
    RYL(3, 16)  RYR(0, 17)  cx_xr<1>(a, (lane & 8) != 0);    // ry w9, ry w10, cx(9,10)
    RYR(3, 18)  RYR(4, 19)  cx_xr<1>(a, (lane & 8) != 0);    // ry w13, ry w14, cx(9,10)
    RYR(2, 19)  RYR(1, 20)  cx_rr<4, 2>(a);                  // ry w2, ry w5, cx(2,5)
    RYR(0, 21)  RYR(3, 22)  cx_rr<8, 1>(a);                  // ry w10, ry w13, cx(13,10)
    RYR(1, 23)  RYR(0, 24)                                   // ry w5, ry w10
    RYL(0, 25)  RYR(1, 26)  cx_xr<2>(a, (lane & 1) != 0);    // ry w0, ry w5, cx(0,5)
    RYR(0, 27)  RYR(4, 28)  cx_rr<16, 1>(a);                 // ry w10, ry w14, cx(14,10)
    RYR(1, 29)  RYR(0, 30)                                   // ry w5, ry w10

#undef RYR
#undef RYL
#undef RYW

    // expz: wire5 -> physical bit 1, wire10 -> physical bit 0 (both register bits)
    float z5 = 0.f, z10 = 0.f;
#pragma unroll
    for (int r = 0; r < 32; r++) {
        float v = a[r] * a[r];
        z5  += (r & 2) ? -v : v;
        z10 += (r & 1) ? -v : v;
    }
#pragma unroll
    for (int o = 32; o > 0; o >>= 1) {
        z5  += __shfl_xor(z5, o, 64);
        z10 += __shfl_xor(z10, o, 64);
    }
    if (lane == 0) { red[wv] = z5; red[16 + wv] = z10; }
    __syncthreads();
    if (tid == 0) {
        float a5 = 0.f, a10 = 0.f;
#pragma unroll
        for (int k = 0; k < 16; k++) { a5 += red[k]; a10 += red[16 + k]; }
        const float PI_ = 3.14159265358979323846f;
        Hout[n * 5 + 0] = PI_ * (1.f - a5);
        Hout[n * 5 + 1] = PI_ * (1.f - a10);
        Hout[n * 5 + 2] = X[n * 3 + 0];
        Hout[n * 5 + 3] = X[n * 3 + 1];
        Hout[n * 5 + 4] = X[n * 3 + 2];
    }
}

// ---------------------------------------------------------------------------
extern "C" void kernel_launch(void* const* d_in, const int* in_sizes, int n_in,
                              void* d_out, int out_size, void* d_ws, size_t ws_size,
                              hipStream_t stream)
{
    const float* X    = (const float*)d_in[0];
    const float* Ri   = (const float*)d_in[1];
    const float* Ro   = (const float*)d_in[2];
    const float* W    = (const float*)d_in[3];
    const float* th_e = (const float*)d_in[4];
    const float* th_n = (const float*)d_in[5];
    float* out = (float*)d_out;

    float* Ha  = (float*)d_ws;
    float* Hb  = Ha + N_NODES * 5;
    float* ev  = Hb + N_NODES * 5;
    int*   snd = (int*)(ev + N_EDGES);
    int*   rcv = snd + N_EDGES;

    (void)hipFuncSetAttribute((const void*)node_kernel,
                              hipFuncAttributeMaxDynamicSharedMemorySize, 131072);

    prep_kernel<<<(N_EDGES + N_NODES + 255) / 256, 256, 0, stream>>>(X, Ri, Ro, W, snd, rcv, Ha);
    edge_kernel<<<N_EDGES, 64, 0, stream>>>(Ha, snd, rcv, th_e, ev);
    node_kernel<<<N_NODES, 1024, 131072, stream>>>(Ha, ev, snd, rcv, th_n, X, Hb);
    edge_kernel<<<N_EDGES, 64, 0, stream>>>(Hb, snd, rcv, th_e, ev);
    node_kernel<<<N_NODES, 1024, 131072, stream>>>(Hb, ev, snd, rcv, th_n, X, Ha);
    edge_kernel<<<N_EDGES, 64, 0, stream>>>(Ha, snd, rcv, th_e, out);
}

// Round 5
// 271.599 us; speedup vs baseline: 1.5705x; 1.0066x over previous
//
#include <hip/hip_runtime.h>
#include <math.h>

#define N_NODES 384
#define N_EDGES 1280

// ---------------------------------------------------------------------------
// BISECTION ROUND: all lane exchanges via __shfl_xor (known-good from rounds
// 1-2). DPP/permlane variants are suspects for the r3/r4 norm-breaking
// failures and are removed entirely.
// ---------------------------------------------------------------------------
template <int M>
__device__ __forceinline__ float lxor_f(float x)
{
    return __shfl_xor(x, M, 64);
}

// ---------------------------------------------------------------------------
// Gate helpers, templated on per-thread register count N.
// ---------------------------------------------------------------------------
template <int N, int M>         // RY on a register bit
__device__ __forceinline__ void ry_r(float (&a)[N], float c_, float s_)
{
#pragma unroll
    for (int r = 0; r < N; r++)
        if ((r & M) == 0) {
            float a0 = a[r], a1 = a[r | M];
            a[r]     = c_ * a0 - s_ * a1;
            a[r | M] = s_ * a0 + c_ * a1;
        }
}

template <int N, int LM>        // RY on a lane bit
__device__ __forceinline__ void ry_l(float (&a)[N], int lane, float c_, float s_)
{
    const float ss = (lane & LM) ? s_ : -s_;
#pragma unroll
    for (int r = 0; r < N; r++) {
        float o = lxor_f<LM>(a[r]);
        a[r] = fmaf(ss, o, c_ * a[r]);
    }
}

template <int N, int TM>        // CX, bool ctrl, lane-bit target
__device__ __forceinline__ void cx_tl(float (&a)[N], bool ctrl)
{
#pragma unroll
    for (int r = 0; r < N; r++) {
        float o = lxor_f<TM>(a[r]);
        a[r] = ctrl ? o : a[r];
    }
}

template <int N, int TM>        // CX, bool ctrl, register-bit target
__device__ __forceinline__ void cx_tr(float (&a)[N], bool ctrl)
{
#pragma unroll
    for (int r = 0; r < N; r++)
        if ((r & TM) == 0) {
            float a0 = a[r], a1 = a[r | TM];
            a[r]      = ctrl ? a1 : a0;
            a[r | TM] = ctrl ? a0 : a1;
        }
}

template <int N, int CM, int TM>  // CX, register ctrl + register target (pure rename)
__device__ __forceinline__ void cx_rr(float (&a)[N])
{
#pragma unroll
    for (int r = 0; r < N; r++)
        if ((r & CM) && !(r & TM)) {
            float t = a[r]; a[r] = a[r | TM]; a[r | TM] = t;
        }
}

// ---------------------------------------------------------------------------
// prep: coalesced one-hot decode + H0 + theta trig tables
// ---------------------------------------------------------------------------
__global__ __launch_bounds__(256) void prep_kernel(
    const float* __restrict__ X, const float* __restrict__ Ri,
    const float* __restrict__ Ro, const float* __restrict__ W,
    const float* __restrict__ th_e, const float* __restrict__ th_n,
    int* __restrict__ snd, int* __restrict__ rcv, float* __restrict__ H0,
    float* __restrict__ cte, float* __restrict__ ste,
    float* __restrict__ ctn, float* __restrict__ stn)
{
    int idx = blockIdx.x * blockDim.x + threadIdx.x;
    if (idx < N_NODES * N_EDGES) {
        int n = idx / N_EDGES, e = idx - n * N_EDGES;
        if (Ro[idx] > 0.5f) snd[e] = n;
        if (Ri[idx] > 0.5f) rcv[e] = n;
    }
    if (idx < N_NODES) {
        int n = idx;
        float x0 = X[n * 3 + 0], x1 = X[n * 3 + 1], x2 = X[n * 3 + 2];
        float t0 = x0 * W[0] + x1 * W[2] + x2 * W[4];
        float t1 = x0 * W[1] + x1 * W[3] + x2 * W[5];
        const float TP = 6.2831853071795864769f;
        H0[n * 5 + 0] = TP / (1.f + expf(-t0));
        H0[n * 5 + 1] = TP / (1.f + expf(-t1));
        H0[n * 5 + 2] = x0;
        H0[n * 5 + 3] = x1;
        H0[n * 5 + 4] = x2;
    } else if (idx >= 512 && idx < 512 + 19) {
        int j = idx - 512;
        float h = 0.5f * th_e[j];
        cte[j] = cosf(h); ste[j] = sinf(h);
    } else if (idx >= 576 && idx < 576 + 31) {
        int j = idx - 576;
        float h = 0.5f * th_n[j];
        ctn[j] = cosf(h); stn[j] = sinf(h);
    }
}

// ---------------------------------------------------------------------------
// edge aggregation: M[n] = [mi(5), mo(5)] via global atomics
// ---------------------------------------------------------------------------
__global__ __launch_bounds__(256) void agg_kernel(
    const float* __restrict__ H, const float* __restrict__ ev,
    const int* __restrict__ snd, const int* __restrict__ rcv,
    float* __restrict__ M)
{
    int e = blockIdx.x * blockDim.x + threadIdx.x;
    if (e < N_EDGES) {
        int se = snd[e], re = rcv[e];
        float w = ev[e];
#pragma unroll
        for (int k = 0; k < 5; k++) atomicAdd(&M[re * 10 + k], w * H[se * 5 + k]);
#pragma unroll
        for (int k = 0; k < 5; k++) atomicAdd(&M[se * 10 + 5 + k], w * H[re * 5 + k]);
    }
}

// ---------------------------------------------------------------------------
// edge circuit: 10 qubits, one wave per edge, 16 amps/lane in registers.
// i = lane*16 + r; bit b <-> wire 9-b. Lane masks: wire w (0-5) -> 1<<(5-w).
// Register bits: wire6->8, wire7->4, wire8->2, wire9->1.
// Also zeroes M (first 60 blocks) for the following agg pass.
// ---------------------------------------------------------------------------
__global__ __launch_bounds__(64) void edge_kernel(
    const float* __restrict__ H, const int* __restrict__ snd, const int* __restrict__ rcv,
    const float* __restrict__ cte, const float* __restrict__ ste,
    float* __restrict__ out, float* __restrict__ M)
{
    const int e = blockIdx.x;
    const int lane = threadIdx.x;

    if (e < 60) M[e * 64 + lane] = 0.f;   // zero M for next agg (3840 = 60*64)

    float f[10];
    const float* hs = H + snd[e] * 5;
    const float* hr = H + rcv[e] * 5;
#pragma unroll
    for (int k = 0; k < 5; k++) { f[k] = hs[k]; f[5 + k] = hr[k]; }

    float cw[10], sw[10];
#pragma unroll
    for (int w = 0; w < 10; w++) {
        float h = 0.5f * f[w];
        sw[w] = sinf(h);
        cw[w] = cosf(h);
    }

    float plane = 1.f;
#pragma unroll
    for (int lb = 0; lb < 6; lb++) {
        int bit = (lane >> lb) & 1;
        plane *= bit ? sw[5 - lb] : cw[5 - lb];
    }
    float a[16];
#pragma unroll
    for (int r = 0; r < 16; r++) {
        float p = plane;
#pragma unroll
        for (int bb = 0; bb < 4; bb++) {
            int bit = (r >> bb) & 1;
            p *= bit ? sw[9 - bb] : cw[9 - bb];
        }
        a[r] = p;
    }

#define RL(M_, I) ry_l<16, M_>(a, lane, cte[I], ste[I]);
#define RR(M_, I) ry_r<16, M_>(a, cte[I], ste[I]);
    RL(32, 0)  RL(16, 1)  cx_tl<16, 16>(a, (lane & 32) != 0);   // ry0 ry1 cx(0,1)
    RL(8, 2)   RL(4, 3)   cx_tl<16, 8>(a, (lane & 4) != 0);     // ry2 ry3 cx(3,2)
    RL(2, 4)   RL(1, 5)   cx_tl<16, 2>(a, (lane & 1) != 0);     // ry4 ry5 cx(5,4)
    RR(8, 6)   RR(4, 7)   cx_rr<16, 8, 4>(a);                   // ry6 ry7 cx(6,7)
    RR(2, 8)   RR(1, 9)   cx_rr<16, 2, 1>(a);                   // ry8 ry9 cx(8,9)
    RL(16, 10) RL(8, 11)  cx_tl<16, 8>(a, (lane & 16) != 0);    // ry1 ry2 cx(1,2)
    RR(4, 12)  RR(1, 13)  cx_rr<16, 1, 4>(a);                   // ry7 ry9 cx(9,7)
    RL(8, 14)  RL(2, 15)  cx_tl<16, 2>(a, (lane & 8) != 0);     // ry2 ry4 cx(2,4)
    RL(2, 16)  RR(4, 17)  cx_tr<16, 4>(a, (lane & 2) != 0);     // ry4 ry7 cx(4,7)
    RR(4, 18)                                                   // ry7
#undef RL
#undef RR

    // expz wire7 -> register bit 4
    float z = 0.f;
#pragma unroll
    for (int r = 0; r < 16; r++) {
        float v = a[r] * a[r];
        z += (r & 4) ? -v : v;
    }
#pragma unroll
    for (int o = 32; o > 0; o >>= 1) z += __shfl_xor(z, o, 64);
    if (lane == 0) out[e] = 0.5f * (1.f - z);
}

// ---------------------------------------------------------------------------
// node circuit: 15 qubits, 32768 amps in registers across 1024 threads.
// i = wave(4b) | lane(6b) | reg(5b).  Physical bit -> wire:
//   reg  pb0..4  : {10, 5, 2, 13, 14}
//   lane pb5..10 : {9, 1, 12, 6, 8, 0}   (masks 1,2,4,8,16,32)
//   wave pb11..14: {3, 4, 7, 11}         (1 RY each -> LDS exchange)
// Wave-bit exchange is CHUNKED: 2 half-exchanges (16 regs) through a 64 KiB
// buffer -> 2 blocks/CU (vs 1 with a 128 KiB buffer) -> 8 waves/SIMD.
// ---------------------------------------------------------------------------
template <int K>        // wave-bit RY: chunked LDS float4 exchange
__device__ __forceinline__ void ry_w(float (&a)[32], float* sh, int tid, float c_, float s_)
{
    float4* v4 = (float4*)sh;                       // 4096 float4 = 64 KiB
    const int pt = tid ^ (64 << K);
    const float ss = (tid & (64 << K)) ? s_ : -s_;
#pragma unroll
    for (int h = 0; h < 2; h++) {                   // two chunks of 16 floats
        __syncthreads();                            // protect prior reads
#pragma unroll
        for (int j = 0; j < 4; j++)
            v4[tid * 4 + j] = make_float4(a[16*h + 4*j + 0], a[16*h + 4*j + 1],
                                          a[16*h + 4*j + 2], a[16*h + 4*j + 3]);
        __syncthreads();
#pragma unroll
        for (int j = 0; j < 4; j++) {
            float4 o = v4[pt * 4 + j];
            a[16*h + 4*j + 0] = fmaf(ss, o.x, c_ * a[16*h + 4*j + 0]);
            a[16*h + 4*j + 1] = fmaf(ss, o.y, c_ * a[16*h + 4*j + 1]);
            a[16*h + 4*j + 2] = fmaf(ss, o.z, c_ * a[16*h + 4*j + 2]);
            a[16*h + 4*j + 3] = fmaf(ss, o.w, c_ * a[16*h + 4*j + 3]);
        }
    }
}

__global__ __launch_bounds__(1024, 8) void node_kernel(
    const float* __restrict__ H, const float* __restrict__ M,
    const float* __restrict__ ctn, const float* __restrict__ stn,
    const float* __restrict__ X, float* __restrict__ Hout)
{
    extern __shared__ float sh[];               // 16384 floats = 64 KiB
    const int n = blockIdx.x;
    const int tid = threadIdx.x;
    const int lane = tid & 63;
    const int wv = tid >> 6;

    __shared__ float cw[15], sw[15];            // feature trig, indexed by PHYSICAL bit
    __shared__ float red[32];

    if (tid < 15) {
        const int wire_of_pb[15] = {10, 5, 2, 13, 14, 9, 1, 12, 6, 8, 0, 3, 4, 7, 11};
        int w_ = wire_of_pb[tid];
        float ang = (w_ < 10) ? M[n * 10 + w_] : H[n * 5 + (w_ - 10)];
        float h = 0.5f * ang;
        sw[tid] = sinf(h);
        cw[tid] = cosf(h);
    }
    __syncthreads();

    // product state
    float pw = 1.f;
#pragma unroll
    for (int k = 0; k < 6; k++) pw *= ((lane >> k) & 1) ? sw[5 + k] : cw[5 + k];
#pragma unroll
    for (int k = 0; k < 4; k++) pw *= ((wv >> k) & 1) ? sw[11 + k] : cw[11 + k];
    float a[32];
#pragma unroll
    for (int r = 0; r < 32; r++) {
        float p = pw;
#pragma unroll
        for (int j = 0; j < 5; j++) p *= ((r >> j) & 1) ? sw[j] : cw[j];
        a[r] = p;
    }

#define RYR(M_, I) ry_r<32, M_>(a, ctn[I], stn[I]);
#define RYL(M_, I) ry_l<32, M_>(a, lane, ctn[I], stn[I]);
#define RYW(K, I)  ry_w<K>(a, sh, tid, ctn[I], stn[I]);

    RYL(32, 0)  RYL(2, 1)   cx_tl<32, 2>(a, (lane & 32) != 0);   // ry0 ry1 cx(0,1)
    RYR(4, 2)   RYW(0, 3)   cx_tr<32, 4>(a, (wv & 1) != 0);      // ry2 ry3 cx(3,2)
    RYW(1, 4)   RYR(2, 5)   cx_tr<32, 2>(a, (wv & 2) != 0);      // ry4 ry5 cx(4,5)
    RYL(8, 6)   RYW(2, 7)   cx_tl<32, 8>(a, (wv & 4) != 0);      // ry6 ry7 cx(7,6)
    RYL(16, 8)  RYL(1, 9)   cx_tl<32, 1>(a, (lane & 16) != 0);   // ry8 ry9 cx(8,9)
    RYR(1, 10)  RYW(3, 11)  cx_tr<32, 1>(a, (wv & 8) != 0);      // ry10 ry11 cx(11,10)
    RYL(4, 12)  RYR(8, 13)  cx_tl<32, 1>(a, (lane & 16) != 0);   // ry12 ry13 cx(8,9)
    RYR(16, 14)                                                  // ry14
    RYL(2, 15)  RYR(4, 16)  cx_tr<32, 4>(a, (lane & 2) != 0);    // ry1 ry2 cx(1,2)
    RYR(2, 14)  RYL(8, 15)  cx_tr<32, 2>(a, (lane & 8) != 0);    // ry5 ry6 cx(6,5)
    RYL(1, 16)  RYR(1, 17)  cx_tr<32, 1>(a, (lane & 1) != 0);    // ry9 ry10 cx(9,10)
    RYR(8, 18)  RYR(16, 19) cx_tr<32, 1>(a, (lane & 1) != 0);    // ry13 ry14 cx(9,10)
    RYR(4, 19)  RYR(2, 20)  cx_rr<32, 4, 2>(a);                  // ry2 ry5 cx(2,5)
    RYR(1, 21)  RYR(8, 22)  cx_rr<32, 8, 1>(a);                  // ry10 ry13 cx(13,10)
    RYR(2, 23)  RYR(1, 24)                                       // ry5 ry10
    RYL(32, 25) RYR(2, 26)  cx_tr<32, 2>(a, (lane & 32) != 0);   // ry0 ry5 cx(0,5)
    RYR(1, 27)  RYR(16, 28) cx_rr<32, 16, 1>(a);                 // ry10 ry14 cx(14,10)
    RYR(2, 29)  RYR(1, 30)                                       // ry5 ry10

#undef RYR
#undef RYL
#undef RYW

    // expz: wire5 -> pb1 (reg m2), wire10 -> pb0 (reg m1)
    float z5 = 0.f, z10 = 0.f;
#pragma unroll
    for (int r = 0; r < 32; r++) {
        float v = a[r] * a[r];
        z5  += (r & 2) ? -v : v;
        z10 += (r & 1) ? -v : v;
    }
#pragma unroll
    for (int o = 32; o > 0; o >>= 1) {
        z5  += __shfl_xor(z5, o, 64);
        z10 += __shfl_xor(z10, o, 64);
    }
    if (lane == 0) { red[wv] = z5; red[16 + wv] = z10; }
    __syncthreads();
    if (tid == 0) {
        float a5 = 0.f, a10 = 0.f;
#pragma unroll
        for (int k = 0; k < 16; k++) { a5 += red[k]; a10 += red[16 + k]; }
        const float PI_ = 3.14159265358979323846f;
        Hout[n * 5 + 0] = PI_ * (1.f - a5);
        Hout[n * 5 + 1] = PI_ * (1.f - a10);
        Hout[n * 5 + 2] = X[n * 3 + 0];
        Hout[n * 5 + 3] = X[n * 3 + 1];
        Hout[n * 5 + 4] = X[n * 3 + 2];
    }
}

// ---------------------------------------------------------------------------
extern "C" void kernel_launch(void* const* d_in, const int* in_sizes, int n_in,
                              void* d_out, int out_size, void* d_ws, size_t ws_size,
                              hipStream_t stream)
{
    const float* X    = (const float*)d_in[0];
    const float* Ri   = (const float*)d_in[1];
    const float* Ro   = (const float*)d_in[2];
    const float* W    = (const float*)d_in[3];
    const float* th_e = (const float*)d_in[4];
    const float* th_n = (const float*)d_in[5];
    float* out = (float*)d_out;

    float* Ha  = (float*)d_ws;              // 1920
    float* Hb  = Ha + N_NODES * 5;          // 1920
    float* ev  = Hb + N_NODES * 5;          // 1280
    int*   snd = (int*)(ev + N_EDGES);      // 1280
    int*   rcv = snd + N_EDGES;             // 1280
    float* M   = (float*)(rcv + N_EDGES);   // 3840
    float* cte = M + N_NODES * 10;          // 19
    float* ste = cte + 19;                  // 19
    float* ctn = ste + 19;                  // 31
    float* stn = ctn + 31;                  // 31

    (void)hipFuncSetAttribute((const void*)node_kernel,
                              hipFuncAttributeMaxDynamicSharedMemorySize, 65536);

    prep_kernel<<<(N_NODES * N_EDGES + 255) / 256, 256, 0, stream>>>(
        X, Ri, Ro, W, th_e, th_n, snd, rcv, Ha, cte, ste, ctn, stn);

    edge_kernel<<<N_EDGES, 64, 0, stream>>>(Ha, snd, rcv, cte, ste, ev, M);
    agg_kernel<<<(N_EDGES + 255) / 256, 256, 0, stream>>>(Ha, ev, snd, rcv, M);
    node_kernel<<<N_NODES, 1024, 65536, stream>>>(Ha, M, ctn, stn, X, Hb);

    edge_kernel<<<N_EDGES, 64, 0, stream>>>(Hb, snd, rcv, cte, ste, ev, M);
    agg_kernel<<<(N_EDGES + 255) / 256, 256, 0, stream>>>(Hb, ev, snd, rcv, M);
    node_kernel<<<N_NODES, 1024, 65536, stream>>>(Hb, M, ctn, stn, X, Ha);

    edge_kernel<<<N_EDGES, 64, 0, stream>>>(Ha, snd, rcv, cte, ste, out, M);
}

// Round 6
// 229.993 us; speedup vs baseline: 1.8546x; 1.1809x over previous
//
#include <hip/hip_runtime.h>
#include <math.h>

#define N_NODES 384
#define N_EDGES 1280

// ---------------------------------------------------------------------------
// Lane-exchange: DPP for xor masks 1,2,8 (VALU pipe, row-local, exact):
//   xor1 = quad_perm [1,0,3,2] (0xB1); xor2 = quad_perm [2,3,0,1] (0x4E);
//   xor8 = row_ror:8 (0x128) — rotate by 8 in a 16-lane row == xor 8.
// Masks 4,16,32 stay on __shfl_xor (known-good r5). Permlane swaps banned
// (r3/r4 suspects). If THIS round fails, DPP is condemned.
// ---------------------------------------------------------------------------
template <int M>
__device__ __forceinline__ float lxor_f(float x)
{
    if constexpr (M == 1) {
        return __builtin_bit_cast(float, __builtin_amdgcn_mov_dpp(
            __builtin_bit_cast(int, x), 0xB1, 0xF, 0xF, true));
    } else if constexpr (M == 2) {
        return __builtin_bit_cast(float, __builtin_amdgcn_mov_dpp(
            __builtin_bit_cast(int, x), 0x4E, 0xF, 0xF, true));
    } else if constexpr (M == 8) {
        return __builtin_bit_cast(float, __builtin_amdgcn_mov_dpp(
            __builtin_bit_cast(int, x), 0x128, 0xF, 0xF, true));
    } else {
        return __shfl_xor(x, M, 64);        // masks 4, 16, 32
    }
}

// ---------------------------------------------------------------------------
// Gate helpers, templated on per-thread register count N.
// ---------------------------------------------------------------------------
template <int N, int M>         // RY on a register bit
__device__ __forceinline__ void ry_r(float (&a)[N], float c_, float s_)
{
#pragma unroll
    for (int r = 0; r < N; r++)
        if ((r & M) == 0) {
            float a0 = a[r], a1 = a[r | M];
            a[r]     = c_ * a0 - s_ * a1;
            a[r | M] = s_ * a0 + c_ * a1;
        }
}

template <int N, int LM>        // RY on a lane bit
__device__ __forceinline__ void ry_l(float (&a)[N], int lane, float c_, float s_)
{
    const float ss = (lane & LM) ? s_ : -s_;
#pragma unroll
    for (int r = 0; r < N; r++) {
        float o = lxor_f<LM>(a[r]);
        a[r] = fmaf(ss, o, c_ * a[r]);
    }
}

template <int N, int TM>        // CX, bool ctrl, lane-bit target
__device__ __forceinline__ void cx_tl(float (&a)[N], bool ctrl)
{
#pragma unroll
    for (int r = 0; r < N; r++) {
        float o = lxor_f<TM>(a[r]);
        a[r] = ctrl ? o : a[r];
    }
}

template <int N, int TM>        // CX, bool ctrl, register-bit target
__device__ __forceinline__ void cx_tr(float (&a)[N], bool ctrl)
{
#pragma unroll
    for (int r = 0; r < N; r++)
        if ((r & TM) == 0) {
            float a0 = a[r], a1 = a[r | TM];
            a[r]      = ctrl ? a1 : a0;
            a[r | TM] = ctrl ? a0 : a1;
        }
}

template <int N, int CM, int TM>  // CX, register ctrl + register target (pure rename)
__device__ __forceinline__ void cx_rr(float (&a)[N])
{
#pragma unroll
    for (int r = 0; r < N; r++)
        if ((r & CM) && !(r & TM)) {
            float t = a[r]; a[r] = a[r | TM]; a[r | TM] = t;
        }
}

// ---------------------------------------------------------------------------
// prep: coalesced one-hot decode + H0 + theta trig tables
// ---------------------------------------------------------------------------
__global__ __launch_bounds__(256) void prep_kernel(
    const float* __restrict__ X, const float* __restrict__ Ri,
    const float* __restrict__ Ro, const float* __restrict__ W,
    const float* __restrict__ th_e, const float* __restrict__ th_n,
    int* __restrict__ snd, int* __restrict__ rcv, float* __restrict__ H0,
    float* __restrict__ cte, float* __restrict__ ste,
    float* __restrict__ ctn, float* __restrict__ stn)
{
    int idx = blockIdx.x * blockDim.x + threadIdx.x;
    if (idx < N_NODES * N_EDGES) {
        int n = idx / N_EDGES, e = idx - n * N_EDGES;
        if (Ro[idx] > 0.5f) snd[e] = n;
        if (Ri[idx] > 0.5f) rcv[e] = n;
    }
    if (idx < N_NODES) {
        int n = idx;
        float x0 = X[n * 3 + 0], x1 = X[n * 3 + 1], x2 = X[n * 3 + 2];
        float t0 = x0 * W[0] + x1 * W[2] + x2 * W[4];
        float t1 = x0 * W[1] + x1 * W[3] + x2 * W[5];
        const float TP = 6.2831853071795864769f;
        H0[n * 5 + 0] = TP / (1.f + expf(-t0));
        H0[n * 5 + 1] = TP / (1.f + expf(-t1));
        H0[n * 5 + 2] = x0;
        H0[n * 5 + 3] = x1;
        H0[n * 5 + 4] = x2;
    } else if (idx >= 512 && idx < 512 + 19) {
        int j = idx - 512;
        float h = 0.5f * th_e[j];
        cte[j] = cosf(h); ste[j] = sinf(h);
    } else if (idx >= 576 && idx < 576 + 31) {
        int j = idx - 576;
        float h = 0.5f * th_n[j];
        ctn[j] = cosf(h); stn[j] = sinf(h);
    }
}

// ---------------------------------------------------------------------------
// edge aggregation: M[n] = [mi(5), mo(5)] via global atomics
// ---------------------------------------------------------------------------
__global__ __launch_bounds__(256) void agg_kernel(
    const float* __restrict__ H, const float* __restrict__ ev,
    const int* __restrict__ snd, const int* __restrict__ rcv,
    float* __restrict__ M)
{
    int e = blockIdx.x * blockDim.x + threadIdx.x;
    if (e < N_EDGES) {
        int se = snd[e], re = rcv[e];
        float w = ev[e];
#pragma unroll
        for (int k = 0; k < 5; k++) atomicAdd(&M[re * 10 + k], w * H[se * 5 + k]);
#pragma unroll
        for (int k = 0; k < 5; k++) atomicAdd(&M[se * 10 + 5 + k], w * H[re * 5 + k]);
    }
}

// ---------------------------------------------------------------------------
// edge circuit: 10 qubits, one wave per edge, 16 amps/lane in registers.
// i = lane*16 + r; bit b <-> wire 9-b. Lane masks: wire w (0-5) -> 1<<(5-w).
// Register bits: wire6->8, wire7->4, wire8->2, wire9->1.
// Also zeroes M (first 60 blocks) for the following agg pass.
// ---------------------------------------------------------------------------
__global__ __launch_bounds__(64) void edge_kernel(
    const float* __restrict__ H, const int* __restrict__ snd, const int* __restrict__ rcv,
    const float* __restrict__ cte, const float* __restrict__ ste,
    float* __restrict__ out, float* __restrict__ M)
{
    const int e = blockIdx.x;
    const int lane = threadIdx.x;

    if (e < 60) M[e * 64 + lane] = 0.f;   // zero M for next agg (3840 = 60*64)

    float f[10];
    const float* hs = H + snd[e] * 5;
    const float* hr = H + rcv[e] * 5;
#pragma unroll
    for (int k = 0; k < 5; k++) { f[k] = hs[k]; f[5 + k] = hr[k]; }

    float cw[10], sw[10];
#pragma unroll
    for (int w = 0; w < 10; w++) {
        float h = 0.5f * f[w];
        sw[w] = sinf(h);
        cw[w] = cosf(h);
    }

    float plane = 1.f;
#pragma unroll
    for (int lb = 0; lb < 6; lb++) {
        int bit = (lane >> lb) & 1;
        plane *= bit ? sw[5 - lb] : cw[5 - lb];
    }
    float a[16];
#pragma unroll
    for (int r = 0; r < 16; r++) {
        float p = plane;
#pragma unroll
        for (int bb = 0; bb < 4; bb++) {
            int bit = (r >> bb) & 1;
            p *= bit ? sw[9 - bb] : cw[9 - bb];
        }
        a[r] = p;
    }

#define RL(M_, I) ry_l<16, M_>(a, lane, cte[I], ste[I]);
#define RR(M_, I) ry_r<16, M_>(a, cte[I], ste[I]);
    RL(32, 0)  RL(16, 1)  cx_tl<16, 16>(a, (lane & 32) != 0);   // ry0 ry1 cx(0,1)
    RL(8, 2)   RL(4, 3)   cx_tl<16, 8>(a, (lane & 4) != 0);     // ry2 ry3 cx(3,2)
    RL(2, 4)   RL(1, 5)   cx_tl<16, 2>(a, (lane & 1) != 0);     // ry4 ry5 cx(5,4)
    RR(8, 6)   RR(4, 7)   cx_rr<16, 8, 4>(a);                   // ry6 ry7 cx(6,7)
    RR(2, 8)   RR(1, 9)   cx_rr<16, 2, 1>(a);                   // ry8 ry9 cx(8,9)
    RL(16, 10) RL(8, 11)  cx_tl<16, 8>(a, (lane & 16) != 0);    // ry1 ry2 cx(1,2)
    RR(4, 12)  RR(1, 13)  cx_rr<16, 1, 4>(a);                   // ry7 ry9 cx(9,7)
    RL(8, 14)  RL(2, 15)  cx_tl<16, 2>(a, (lane & 8) != 0);     // ry2 ry4 cx(2,4)
    RL(2, 16)  RR(4, 17)  cx_tr<16, 4>(a, (lane & 2) != 0);     // ry4 ry7 cx(4,7)
    RR(4, 18)                                                   // ry7
#undef RL
#undef RR

    // expz wire7 -> register bit 4
    float z = 0.f;
#pragma unroll
    for (int r = 0; r < 16; r++) {
        float v = a[r] * a[r];
        z += (r & 4) ? -v : v;
    }
#pragma unroll
    for (int o = 32; o > 0; o >>= 1) z += __shfl_xor(z, o, 64);
    if (lane == 0) out[e] = 0.5f * (1.f - z);
}

// ---------------------------------------------------------------------------
// node circuit: 15 qubits, 32768 amps in registers across 1024 threads.
// i = wave(4b) | lane(6b) | reg(5b).  Physical bit -> wire:
//   reg  pb0..4  : {10, 5, 2, 13, 14}
//   lane pb5..10 : {9, 1, 12, 6, 8, 0}   (masks 1,2,4,8,16,32)
//   wave pb11..14: {3, 4, 7, 11}         (1 RY each -> LDS exchange)
// Wave-bit exchange chunked through 64 KiB. launch_bounds(1024, 4): r5's
// (1024,8) forced VGPR=32 -> scratch traffic (WRITE_SIZE 10.7 MB/dispatch).
// ---------------------------------------------------------------------------
template <int K>        // wave-bit RY: chunked LDS float4 exchange
__device__ __forceinline__ void ry_w(float (&a)[32], float* sh, int tid, float c_, float s_)
{
    float4* v4 = (float4*)sh;                       // 4096 float4 = 64 KiB
    const int pt = tid ^ (64 << K);
    const float ss = (tid & (64 << K)) ? s_ : -s_;
#pragma unroll
    for (int h = 0; h < 2; h++) {                   // two chunks of 16 floats
        __syncthreads();                            // protect prior reads
#pragma unroll
        for (int j = 0; j < 4; j++)
            v4[tid * 4 + j] = make_float4(a[16*h + 4*j + 0], a[16*h + 4*j + 1],
                                          a[16*h + 4*j + 2], a[16*h + 4*j + 3]);
        __syncthreads();
#pragma unroll
        for (int j = 0; j < 4; j++) {
            float4 o = v4[pt * 4 + j];
            a[16*h + 4*j + 0] = fmaf(ss, o.x, c_ * a[16*h + 4*j + 0]);
            a[16*h + 4*j + 1] = fmaf(ss, o.y, c_ * a[16*h + 4*j + 1]);
            a[16*h + 4*j + 2] = fmaf(ss, o.z, c_ * a[16*h + 4*j + 2]);
            a[16*h + 4*j + 3] = fmaf(ss, o.w, c_ * a[16*h + 4*j + 3]);
        }
    }
}

__global__ __launch_bounds__(1024, 4) void node_kernel(
    const float* __restrict__ H, const float* __restrict__ M,
    const float* __restrict__ ctn, const float* __restrict__ stn,
    const float* __restrict__ X, float* __restrict__ Hout)
{
    extern __shared__ float sh[];               // 16384 floats = 64 KiB
    const int n = blockIdx.x;
    const int tid = threadIdx.x;
    const int lane = tid & 63;
    const int wv = tid >> 6;

    __shared__ float cw[15], sw[15];            // feature trig, indexed by PHYSICAL bit
    __shared__ float red[32];

    if (tid < 15) {
        const int wire_of_pb[15] = {10, 5, 2, 13, 14, 9, 1, 12, 6, 8, 0, 3, 4, 7, 11};
        int w_ = wire_of_pb[tid];
        float ang = (w_ < 10) ? M[n * 10 + w_] : H[n * 5 + (w_ - 10)];
        float h = 0.5f * ang;
        sw[tid] = sinf(h);
        cw[tid] = cosf(h);
    }
    __syncthreads();

    // product state
    float pw = 1.f;
#pragma unroll
    for (int k = 0; k < 6; k++) pw *= ((lane >> k) & 1) ? sw[5 + k] : cw[5 + k];
#pragma unroll
    for (int k = 0; k < 4; k++) pw *= ((wv >> k) & 1) ? sw[11 + k] : cw[11 + k];
    float a[32];
#pragma unroll
    for (int r = 0; r < 32; r++) {
        float p = pw;
#pragma unroll
        for (int j = 0; j < 5; j++) p *= ((r >> j) & 1) ? sw[j] : cw[j];
        a[r] = p;
    }

#define RYR(M_, I) ry_r<32, M_>(a, ctn[I], stn[I]);
#define RYL(M_, I) ry_l<32, M_>(a, lane, ctn[I], stn[I]);
#define RYW(K, I)  ry_w<K>(a, sh, tid, ctn[I], stn[I]);

    RYL(32, 0)  RYL(2, 1)   cx_tl<32, 2>(a, (lane & 32) != 0);   // ry0 ry1 cx(0,1)
    RYR(4, 2)   RYW(0, 3)   cx_tr<32, 4>(a, (wv & 1) != 0);      // ry2 ry3 cx(3,2)
    RYW(1, 4)   RYR(2, 5)   cx_tr<32, 2>(a, (wv & 2) != 0);      // ry4 ry5 cx(4,5)
    RYL(8, 6)   RYW(2, 7)   cx_tl<32, 8>(a, (wv & 4) != 0);      // ry6 ry7 cx(7,6)
    RYL(16, 8)  RYL(1, 9)   cx_tl<32, 1>(a, (lane & 16) != 0);   // ry8 ry9 cx(8,9)
    RYR(1, 10)  RYW(3, 11)  cx_tr<32, 1>(a, (wv & 8) != 0);      // ry10 ry11 cx(11,10)
    RYL(4, 12)  RYR(8, 13)  cx_tl<32, 1>(a, (lane & 16) != 0);   // ry12 ry13 cx(8,9)
    RYR(16, 14)                                                  // ry14
    RYL(2, 15)  RYR(4, 16)  cx_tr<32, 4>(a, (lane & 2) != 0);    // ry1 ry2 cx(1,2)
    RYR(2, 14)  RYL(8, 15)  cx_tr<32, 2>(a, (lane & 8) != 0);    // ry5 ry6 cx(6,5)
    RYL(1, 16)  RYR(1, 17)  cx_tr<32, 1>(a, (lane & 1) != 0);    // ry9 ry10 cx(9,10)
    RYR(8, 18)  RYR(16, 19) cx_tr<32, 1>(a, (lane & 1) != 0);    // ry13 ry14 cx(9,10)
    RYR(4, 19)  RYR(2, 20)  cx_rr<32, 4, 2>(a);                  // ry2 ry5 cx(2,5)
    RYR(1, 21)  RYR(8, 22)  cx_rr<32, 8, 1>(a);                  // ry10 ry13 cx(13,10)
    RYR(2, 23)  RYR(1, 24)                                       // ry5 ry10
    RYL(32, 25) RYR(2, 26)  cx_tr<32, 2>(a, (lane & 32) != 0);   // ry0 ry5 cx(0,5)
    RYR(1, 27)  RYR(16, 28) cx_rr<32, 16, 1>(a);                 // ry10 ry14 cx(14,10)
    RYR(2, 29)  RYR(1, 30)                                       // ry5 ry10

#undef RYR
#undef RYL
#undef RYW

    // expz: wire5 -> pb1 (reg m2), wire10 -> pb0 (reg m1)
    float z5 = 0.f, z10 = 0.f;
#pragma unroll
    for (int r = 0; r < 32; r++) {
        float v = a[r] * a[r];
        z5  += (r & 2) ? -v : v;
        z10 += (r & 1) ? -v : v;
    }
#pragma unroll
    for (int o = 32; o > 0; o >>= 1) {
        z5  += __shfl_xor(z5, o, 64);
        z10 += __shfl_xor(z10, o, 64);
    }
    if (lane == 0) { red[wv] = z5; red[16 + wv] = z10; }
    __syncthreads();
    if (tid == 0) {
        float a5 = 0.f, a10 = 0.f;
#pragma unroll
        for (int k = 0; k < 16; k++) { a5 += red[k]; a10 += red[16 + k]; }
        const float PI_ = 3.14159265358979323846f;
        Hout[n * 5 + 0] = PI_ * (1.f - a5);
        Hout[n * 5 + 1] = PI_ * (1.f - a10);
        Hout[n * 5 + 2] = X[n * 3 + 0];
        Hout[n * 5 + 3] = X[n * 3 + 1];
        Hout[n * 5 + 4] = X[n * 3 + 2];
    }
}

// ---------------------------------------------------------------------------
extern "C" void kernel_launch(void* const* d_in, const int* in_sizes, int n_in,
                              void* d_out, int out_size, void* d_ws, size_t ws_size,
                              hipStream_t stream)
{
    const float* X    = (const float*)d_in[0];
    const float* Ri   = (const float*)d_in[1];
    const float* Ro   = (const float*)d_in[2];
    const float* W    = (const float*)d_in[3];
    const float* th_e = (const float*)d_in[4];
    const float* th_n = (const float*)d_in[5];
    float* out = (float*)d_out;

    float* Ha  = (float*)d_ws;              // 1920
    float* Hb  = Ha + N_NODES * 5;          // 1920
    float* ev  = Hb + N_NODES * 5;          // 1280
    int*   snd = (int*)(ev + N_EDGES);      // 1280
    int*   rcv = snd + N_EDGES;             // 1280
    float* M   = (float*)(rcv + N_EDGES);   // 3840
    float* cte = M + N_NODES * 10;          // 19
    float* ste = cte + 19;                  // 19
    float* ctn = ste + 19;                  // 31
    float* stn = ctn + 31;                  // 31

    (void)hipFuncSetAttribute((const void*)node_kernel,
                              hipFuncAttributeMaxDynamicSharedMemorySize, 65536);

    prep_kernel<<<(N_NODES * N_EDGES + 255) / 256, 256, 0, stream>>>(
        X, Ri, Ro, W, th_e, th_n, snd, rcv, Ha, cte, ste, ctn, stn);

    edge_kernel<<<N_EDGES, 64, 0, stream>>>(Ha, snd, rcv, cte, ste, ev, M);
    agg_kernel<<<(N_EDGES + 255) / 256, 256, 0, stream>>>(Ha, ev, snd, rcv, M);
    node_kernel<<<N_NODES, 1024, 65536, stream>>>(Ha, M, ctn, stn, X, Hb);

    edge_kernel<<<N_EDGES, 64, 0, stream>>>(Hb, snd, rcv, cte, ste, ev, M);
    agg_kernel<<<(N_EDGES + 255) / 256, 256, 0, stream>>>(Hb, ev, snd, rcv, M);
    node_kernel<<<N_NODES, 1024, 65536, stream>>>(Hb, M, ctn, stn, X, Ha);

    edge_kernel<<<N_EDGES, 64, 0, stream>>>(Ha, snd, rcv, cte, ste, out, M);
}

// Round 7
// 81.792 us; speedup vs baseline: 5.2149x; 2.8119x over previous
//
#include <hip/hip_runtime.h>
#include <math.h>

#define N_NODES 384
#define N_EDGES 1280

// ---------------------------------------------------------------------------
// Lane-exchange: DPP for xor masks 1,2,8 (VALU pipe, verified passing r6):
//   xor1 = quad_perm [1,0,3,2]; xor2 = quad_perm [2,3,0,1]; xor8 = row_ror:8.
// Masks 4,16,32 -> __shfl_xor. Permlane swaps: BANNED (r3/r4 failures).
// ---------------------------------------------------------------------------
template <int M>
__device__ __forceinline__ float lxor_f(float x)
{
    if constexpr (M == 1) {
        return __builtin_bit_cast(float, __builtin_amdgcn_mov_dpp(
            __builtin_bit_cast(int, x), 0xB1, 0xF, 0xF, true));
    } else if constexpr (M == 2) {
        return __builtin_bit_cast(float, __builtin_amdgcn_mov_dpp(
            __builtin_bit_cast(int, x), 0x4E, 0xF, 0xF, true));
    } else if constexpr (M == 8) {
        return __builtin_bit_cast(float, __builtin_amdgcn_mov_dpp(
            __builtin_bit_cast(int, x), 0x128, 0xF, 0xF, true));
    } else {
        return __shfl_xor(x, M, 64);        // masks 4, 16, 32
    }
}

// ---------------------------------------------------------------------------
// Gate helpers (algebra verified passing in r5/r6), N = regs per thread.
// ---------------------------------------------------------------------------
template <int N, int M>         // RY on a register bit
__device__ __forceinline__ void ry_r(float (&a)[N], float c_, float s_)
{
#pragma unroll
    for (int r = 0; r < N; r++)
        if ((r & M) == 0) {
            float a0 = a[r], a1 = a[r | M];
            a[r]     = c_ * a0 - s_ * a1;
            a[r | M] = s_ * a0 + c_ * a1;
        }
}

template <int N, int LM>        // RY on a lane bit
__device__ __forceinline__ void ry_l(float (&a)[N], int lane, float c_, float s_)
{
    const float ss = (lane & LM) ? s_ : -s_;
#pragma unroll
    for (int r = 0; r < N; r++) {
        float o = lxor_f<LM>(a[r]);
        a[r] = fmaf(ss, o, c_ * a[r]);
    }
}

template <int N, int TM>        // CX, bool ctrl, lane-bit target
__device__ __forceinline__ void cx_tl(float (&a)[N], bool ctrl)
{
#pragma unroll
    for (int r = 0; r < N; r++) {
        float o = lxor_f<TM>(a[r]);
        a[r] = ctrl ? o : a[r];
    }
}

template <int N, int TM>        // CX, bool ctrl, register-bit target
__device__ __forceinline__ void cx_tr(float (&a)[N], bool ctrl)
{
#pragma unroll
    for (int r = 0; r < N; r++)
        if ((r & TM) == 0) {
            float a0 = a[r], a1 = a[r | TM];
            a[r]      = ctrl ? a1 : a0;
            a[r | TM] = ctrl ? a0 : a1;
        }
}

template <int N, int CM, int TM>  // CX, register ctrl + register target (rename)
__device__ __forceinline__ void cx_rr(float (&a)[N])
{
#pragma unroll
    for (int r = 0; r < N; r++)
        if ((r & CM) && !(r & TM)) {
            float t = a[r]; a[r] = a[r | TM]; a[r | TM] = t;
        }
}

// ---------------------------------------------------------------------------
// prep: one-hot decode (coalesced), H0, theta trig tables, zero M
// ---------------------------------------------------------------------------
__global__ __launch_bounds__(256) void prep_kernel(
    const float* __restrict__ X, const float* __restrict__ Ri,
    const float* __restrict__ Ro, const float* __restrict__ W,
    const float* __restrict__ th_e, const float* __restrict__ th_n,
    int* __restrict__ snd, int* __restrict__ rcv, float* __restrict__ H0,
    float* __restrict__ cte, float* __restrict__ ste,
    float* __restrict__ ctn, float* __restrict__ stn,
    float* __restrict__ M)
{
    int idx = blockIdx.x * blockDim.x + threadIdx.x;
    if (idx < N_NODES * N_EDGES) {
        int n = idx / N_EDGES, e = idx - n * N_EDGES;
        if (Ro[idx] > 0.5f) snd[e] = n;
        if (Ri[idx] > 0.5f) rcv[e] = n;
    }
    if (idx < N_NODES) {
        int n = idx;
        float x0 = X[n * 3 + 0], x1 = X[n * 3 + 1], x2 = X[n * 3 + 2];
        float t0 = x0 * W[0] + x1 * W[2] + x2 * W[4];
        float t1 = x0 * W[1] + x1 * W[3] + x2 * W[5];
        const float TP = 6.2831853071795864769f;
        H0[n * 5 + 0] = TP / (1.f + expf(-t0));
        H0[n * 5 + 1] = TP / (1.f + expf(-t1));
        H0[n * 5 + 2] = x0;
        H0[n * 5 + 3] = x1;
        H0[n * 5 + 4] = x2;
    } else if (idx >= 512 && idx < 512 + 19) {
        int j = idx - 512;
        float h = 0.5f * th_e[j];
        cte[j] = cosf(h); ste[j] = sinf(h);
    } else if (idx >= 576 && idx < 576 + 31) {
        int j = idx - 576;
        float h = 0.5f * th_n[j];
        ctn[j] = cosf(h); stn[j] = sinf(h);
    } else if (idx >= 1024 && idx < 1024 + N_NODES * 10) {
        M[idx - 1024] = 0.f;
    }
}

// ---------------------------------------------------------------------------
// edge circuit, FIRST-RY-ABSORBED: init angle A_w = f_w + th_e[w] (w=0..9).
// Remaining 9 RY + 9 CX. 4 edges/block (4 waves), 16 regs/lane.
//   lane bits: m1=w1, m2=w0, m4=w3, m8=w5, m16=w6, m32=w8
//   reg  bits: m1=w7, m2=w2, m4=w4, m8=w9
// Epilogue: fused aggregation (mi/mo atomics into M) -- agg_kernel deleted.
// ---------------------------------------------------------------------------
__global__ __launch_bounds__(256) void edge_kernel(
    const float* __restrict__ H, const int* __restrict__ snd, const int* __restrict__ rcv,
    const float* __restrict__ cte, const float* __restrict__ ste,
    const float* __restrict__ th_e,
    float* __restrict__ out, float* __restrict__ M)
{
    const int e = blockIdx.x * 4 + (threadIdx.x >> 6);
    const int lane = threadIdx.x & 63;
    const int se = snd[e], re = rcv[e];

    float f[10];
#pragma unroll
    for (int k = 0; k < 5; k++) { f[k] = H[se * 5 + k]; f[5 + k] = H[re * 5 + k]; }

    float cw[10], sw[10];
#pragma unroll
    for (int w = 0; w < 10; w++) {
        float h = 0.5f * (f[w] + th_e[w]);      // absorbed first RY
        sw[w] = sinf(h);
        cw[w] = cosf(h);
    }

    float pl = 1.f;
    pl *= (lane & 1)  ? sw[1] : cw[1];
    pl *= (lane & 2)  ? sw[0] : cw[0];
    pl *= (lane & 4)  ? sw[3] : cw[3];
    pl *= (lane & 8)  ? sw[5] : cw[5];
    pl *= (lane & 16) ? sw[6] : cw[6];
    pl *= (lane & 32) ? sw[8] : cw[8];
    float a[16];
#pragma unroll
    for (int r = 0; r < 16; r++) {
        float p = pl;
        p *= (r & 1) ? sw[7] : cw[7];
        p *= (r & 2) ? sw[2] : cw[2];
        p *= (r & 4) ? sw[4] : cw[4];
        p *= (r & 8) ? sw[9] : cw[9];
        a[r] = p;
    }

    cx_tl<16, 1>(a, (lane & 2) != 0);            // cx(0,1)  tgt w1 (DPP)
    cx_tr<16, 2>(a, (lane & 4) != 0);            // cx(3,2)
    cx_tr<16, 4>(a, (lane & 8) != 0);            // cx(5,4)
    cx_tr<16, 1>(a, (lane & 16) != 0);           // cx(6,7)
    cx_tr<16, 8>(a, (lane & 32) != 0);           // cx(8,9)
    ry_l<16, 1>(a, lane, cte[10], ste[10]);      // ry(10,w1) (DPP)
    ry_r<16, 2>(a, cte[11], ste[11]);            // ry(11,w2)
    cx_tr<16, 2>(a, (lane & 1) != 0);            // cx(1,2)
    ry_r<16, 1>(a, cte[12], ste[12]);            // ry(12,w7)
    ry_r<16, 8>(a, cte[13], ste[13]);            // ry(13,w9)
    cx_rr<16, 8, 1>(a);                          // cx(9,7)
    ry_r<16, 2>(a, cte[14], ste[14]);            // ry(14,w2)
    ry_r<16, 4>(a, cte[15], ste[15]);            // ry(15,w4)
    cx_rr<16, 2, 4>(a);                          // cx(2,4)
    ry_r<16, 4>(a, cte[16], ste[16]);            // ry(16,w4)
    ry_r<16, 1>(a, cte[17], ste[17]);            // ry(17,w7)
    cx_rr<16, 4, 1>(a);                          // cx(4,7)
    ry_r<16, 1>(a, cte[18], ste[18]);            // ry(18,w7)

    // expz wire7 -> reg bit m1
    float z = 0.f;
#pragma unroll
    for (int r = 0; r < 16; r++) {
        float v = a[r] * a[r];
        z += (r & 1) ? -v : v;
    }
#pragma unroll
    for (int o = 32; o > 0; o >>= 1) z += __shfl_xor(z, o, 64);   // all lanes get z
    float ev = 0.5f * (1.f - z);

    if (lane == 0) out[e] = ev;
    // fused aggregation: mi[re] += ev*H[se], mo[se] += ev*H[re]
    if (lane < 5)       atomicAdd(&M[re * 10 + lane], ev * f[lane]);
    else if (lane < 10) atomicAdd(&M[se * 10 + lane], ev * f[lane]);
}

// ---------------------------------------------------------------------------
// node circuit, FIRST-RY-ABSORBED + cancelled cx(8,9)^2 and cx(9,10)^2:
// 20 RY + 11 CX remain. 32768 amps in regs across 1024 threads; ZERO LDS
// exchanges (wave wires {3,4,7,11} are control-only after absorption).
//   reg  bits m1,2,4,8,16 = wires {10, 5, 2, 13, 14}
//   lane bits m1,2,4,8,16,32 = wires {9, 1, 0, 6, 8, 12}  (8,12 gate-free)
//   wave bits b0..b3 = wires {3, 4, 7, 11}                (control-only)
// Block re-zeros its own M row after reading (edge pass k+1 re-accumulates).
// ---------------------------------------------------------------------------
__global__ __launch_bounds__(1024, 4) void node_kernel(
    const float* __restrict__ H, float* __restrict__ M,
    const float* __restrict__ ctn, const float* __restrict__ stn,
    const float* __restrict__ th_n,
    const float* __restrict__ X, float* __restrict__ Hout)
{
    const int n = blockIdx.x;
    const int tid = threadIdx.x;
    const int lane = tid & 63;
    const int wv = tid >> 6;

    __shared__ float cw[15], sw[15];            // indexed by PHYSICAL bit
    __shared__ float red[32];

    if (tid < 15) {
        const int wire_of_pb[15] = {10, 5, 2, 13, 14, 9, 1, 0, 6, 8, 12, 3, 4, 7, 11};
        int w_ = wire_of_pb[tid];
        float ang = ((w_ < 10) ? M[n * 10 + w_] : H[n * 5 + (w_ - 10)]) + th_n[w_];
        float h = 0.5f * ang;                   // absorbed first RY
        sw[tid] = sinf(h);
        cw[tid] = cosf(h);
    }
    __syncthreads();
    if (tid < 10) M[n * 10 + tid] = 0.f;        // re-zero own row for next edge pass

    // product state
    float pw = 1.f;
#pragma unroll
    for (int k = 0; k < 6; k++) pw *= ((lane >> k) & 1) ? sw[5 + k] : cw[5 + k];
#pragma unroll
    for (int k = 0; k < 4; k++) pw *= ((wv >> k) & 1) ? sw[11 + k] : cw[11 + k];
    float a[32];
#pragma unroll
    for (int r = 0; r < 32; r++) {
        float p = pw;
#pragma unroll
        for (int j = 0; j < 5; j++) p *= ((r >> j) & 1) ? sw[j] : cw[j];
        a[r] = p;
    }

    cx_tl<32, 2>(a, (lane & 4) != 0);            // cx(0,1)  tgt w1 (DPP)
    cx_tr<32, 4>(a, (wv & 1) != 0);              // cx(3,2)
    cx_tr<32, 2>(a, (wv & 2) != 0);              // cx(4,5)
    cx_tl<32, 8>(a, (wv & 4) != 0);              // cx(7,6)  tgt w6 (DPP)
    cx_tr<32, 1>(a, (wv & 8) != 0);              // cx(11,10)
    ry_l<32, 2>(a, lane, ctn[15], stn[15]);      // ry(15,w1) (DPP)
    ry_r<32, 4>(a, ctn[16], stn[16]);            // ry(16,w2)
    cx_tr<32, 4>(a, (lane & 2) != 0);            // cx(1,2)
    ry_r<32, 2>(a, ctn[14], stn[14]);            // ry(14,w5)
    ry_l<32, 8>(a, lane, ctn[15], stn[15]);      // ry(15,w6) (DPP)
    cx_tr<32, 2>(a, (lane & 8) != 0);            // cx(6,5)
    ry_l<32, 1>(a, lane, ctn[16], stn[16]);      // ry(16,w9) (DPP)
    ry_r<32, 1>(a, ctn[17], stn[17]);            // ry(17,w10)
    ry_r<32, 8>(a, ctn[18], stn[18]);            // ry(18,w13)
    ry_r<32, 16>(a, ctn[19], stn[19]);           // ry(19,w14)
    ry_r<32, 4>(a, ctn[19], stn[19]);            // ry(19,w2)
    ry_r<32, 2>(a, ctn[20], stn[20]);            // ry(20,w5)
    cx_rr<32, 4, 2>(a);                          // cx(2,5)
    ry_r<32, 1>(a, ctn[21], stn[21]);            // ry(21,w10)
    ry_r<32, 8>(a, ctn[22], stn[22]);            // ry(22,w13)
    cx_rr<32, 8, 1>(a);                          // cx(13,10)
    ry_r<32, 2>(a, ctn[23], stn[23]);            // ry(23,w5)
    ry_r<32, 1>(a, ctn[24], stn[24]);            // ry(24,w10)
    ry_l<32, 4>(a, lane, ctn[25], stn[25]);      // ry(25,w0) (the one shfl gate)
    ry_r<32, 2>(a, ctn[26], stn[26]);            // ry(26,w5)
    cx_tr<32, 2>(a, (lane & 4) != 0);            // cx(0,5)
    ry_r<32, 1>(a, ctn[27], stn[27]);            // ry(27,w10)
    ry_r<32, 16>(a, ctn[28], stn[28]);           // ry(28,w14)
    cx_rr<32, 16, 1>(a);                         // cx(14,10)
    ry_r<32, 2>(a, ctn[29], stn[29]);            // ry(29,w5)
    ry_r<32, 1>(a, ctn[30], stn[30]);            // ry(30,w10)

    // expz: wire5 -> m2, wire10 -> m1
    float z5 = 0.f, z10 = 0.f;
#pragma unroll
    for (int r = 0; r < 32; r++) {
        float v = a[r] * a[r];
        z5  += (r & 2) ? -v : v;
        z10 += (r & 1) ? -v : v;
    }
#pragma unroll
    for (int o = 32; o > 0; o >>= 1) {
        z5  += __shfl_xor(z5, o, 64);
        z10 += __shfl_xor(z10, o, 64);
    }
    if (lane == 0) { red[wv] = z5; red[16 + wv] = z10; }
    __syncthreads();
    if (tid == 0) {
        float a5 = 0.f, a10 = 0.f;
#pragma unroll
        for (int k = 0; k < 16; k++) { a5 += red[k]; a10 += red[16 + k]; }
        const float PI_ = 3.14159265358979323846f;
        Hout[n * 5 + 0] = PI_ * (1.f - a5);
        Hout[n * 5 + 1] = PI_ * (1.f - a10);
        Hout[n * 5 + 2] = X[n * 3 + 0];
        Hout[n * 5 + 3] = X[n * 3 + 1];
        Hout[n * 5 + 4] = X[n * 3 + 2];
    }
}

// ---------------------------------------------------------------------------
extern "C" void kernel_launch(void* const* d_in, const int* in_sizes, int n_in,
                              void* d_out, int out_size, void* d_ws, size_t ws_size,
                              hipStream_t stream)
{
    const float* X    = (const float*)d_in[0];
    const float* Ri   = (const float*)d_in[1];
    const float* Ro   = (const float*)d_in[2];
    const float* W    = (const float*)d_in[3];
    const float* th_e = (const float*)d_in[4];
    const float* th_n = (const float*)d_in[5];
    float* out = (float*)d_out;

    float* Ha  = (float*)d_ws;              // 1920
    float* Hb  = Ha + N_NODES * 5;          // 1920
    float* ev  = Hb + N_NODES * 5;          // 1280
    int*   snd = (int*)(ev + N_EDGES);      // 1280
    int*   rcv = snd + N_EDGES;             // 1280
    float* M   = (float*)(rcv + N_EDGES);   // 3840
    float* cte = M + N_NODES * 10;          // 19
    float* ste = cte + 19;                  // 19
    float* ctn = ste + 19;                  // 31
    float* stn = ctn + 31;                  // 31

    prep_kernel<<<(N_NODES * N_EDGES + 255) / 256, 256, 0, stream>>>(
        X, Ri, Ro, W, th_e, th_n, snd, rcv, Ha, cte, ste, ctn, stn, M);

    edge_kernel<<<N_EDGES / 4, 256, 0, stream>>>(Ha, snd, rcv, cte, ste, th_e, ev, M);
    node_kernel<<<N_NODES, 1024, 0, stream>>>(Ha, M, ctn, stn, th_n, X, Hb);

    edge_kernel<<<N_EDGES / 4, 256, 0, stream>>>(Hb, snd, rcv, cte, ste, th_e, ev, M);
    node_kernel<<<N_NODES, 1024, 0, stream>>>(Hb, M, ctn, stn, th_n, X, Ha);

    edge_kernel<<<N_EDGES / 4, 256, 0, stream>>>(Ha, snd, rcv, cte, ste, th_e, out, M);
}

// Round 8
// 78.594 us; speedup vs baseline: 5.4271x; 1.0407x over previous
//
#include <hip/hip_runtime.h>
#include <math.h>

#define N_NODES 384
#define N_EDGES 1280

// ---------------------------------------------------------------------------
// Lane-exchange: DPP for xor masks 1,2,8 (VALU pipe, verified passing r6/r7):
//   xor1 = quad_perm [1,0,3,2]; xor2 = quad_perm [2,3,0,1]; xor8 = row_ror:8.
// Masks 4,16,32 -> __shfl_xor. Permlane swaps: BANNED (r3/r4 failures).
// ---------------------------------------------------------------------------
template <int M>
__device__ __forceinline__ float lxor_f(float x)
{
    if constexpr (M == 1) {
        return __builtin_bit_cast(float, __builtin_amdgcn_mov_dpp(
            __builtin_bit_cast(int, x), 0xB1, 0xF, 0xF, true));
    } else if constexpr (M == 2) {
        return __builtin_bit_cast(float, __builtin_amdgcn_mov_dpp(
            __builtin_bit_cast(int, x), 0x4E, 0xF, 0xF, true));
    } else if constexpr (M == 8) {
        return __builtin_bit_cast(float, __builtin_amdgcn_mov_dpp(
            __builtin_bit_cast(int, x), 0x128, 0xF, 0xF, true));
    } else {
        return __shfl_xor(x, M, 64);        // masks 4, 16, 32
    }
}

// ---------------------------------------------------------------------------
// float2-packed gate helpers. Amp pairing: component (.x/.y) = the LEAST-GATED
// register wire, so nearly all reg-bit RYs are elementwise float2 ops ->
// SLP-vectorizable to v_pk_fma_f32/v_pk_mul_f32. Gate ORDER identical to the
// r7-verified sequence; only the amp indexing changed.
// ---------------------------------------------------------------------------
template <int K, int M>         // RY on a packed-index bit (elementwise f2)
__device__ __forceinline__ void ryr2(float2 (&a)[K], float c_, float s_)
{
#pragma unroll
    for (int k = 0; k < K; k++)
        if ((k & M) == 0) {
            float2 u = a[k], v = a[k | M];
            a[k].x     = c_ * u.x - s_ * v.x;
            a[k].y     = c_ * u.y - s_ * v.y;
            a[k | M].x = s_ * u.x + c_ * v.x;
            a[k | M].y = s_ * u.y + c_ * v.y;
        }
}

template <int K>                // RY on the component bit (scalar rotate)
__device__ __forceinline__ void ryc2(float2 (&a)[K], float c_, float s_)
{
#pragma unroll
    for (int k = 0; k < K; k++) {
        float x = a[k].x, y = a[k].y;
        a[k].x = c_ * x - s_ * y;
        a[k].y = s_ * x + c_ * y;
    }
}

template <int K, int LM>        // RY on a lane bit
__device__ __forceinline__ void ryl2(float2 (&a)[K], int lane, float c_, float s_)
{
    const float ss = (lane & LM) ? s_ : -s_;
#pragma unroll
    for (int k = 0; k < K; k++) {
        float ox = lxor_f<LM>(a[k].x);
        float oy = lxor_f<LM>(a[k].y);
        a[k].x = fmaf(ss, ox, c_ * a[k].x);
        a[k].y = fmaf(ss, oy, c_ * a[k].y);
    }
}

template <int K, int TM>        // CX, bool ctrl, lane-bit target
__device__ __forceinline__ void cxl2(float2 (&a)[K], bool ctrl)
{
#pragma unroll
    for (int k = 0; k < K; k++) {
        float ox = lxor_f<TM>(a[k].x);
        float oy = lxor_f<TM>(a[k].y);
        a[k].x = ctrl ? ox : a[k].x;
        a[k].y = ctrl ? oy : a[k].y;
    }
}

template <int K, int TM>        // CX, bool ctrl, packed-index target
__device__ __forceinline__ void cxr2(float2 (&a)[K], bool ctrl)
{
#pragma unroll
    for (int k = 0; k < K; k++)
        if ((k & TM) == 0) {
            float2 u = a[k], v = a[k | TM];
            a[k].x      = ctrl ? v.x : u.x;
            a[k].y      = ctrl ? v.y : u.y;
            a[k | TM].x = ctrl ? u.x : v.x;
            a[k | TM].y = ctrl ? u.y : v.y;
        }
}

template <int K>                // CX, bool ctrl, COMPONENT target (x<->y)
__device__ __forceinline__ void cxc2(float2 (&a)[K], bool ctrl)
{
#pragma unroll
    for (int k = 0; k < K; k++) {
        float x = a[k].x, y = a[k].y;
        a[k].x = ctrl ? y : x;
        a[k].y = ctrl ? x : y;
    }
}

template <int K, int CM, int TM>  // CX, packed ctrl + packed target (rename)
__device__ __forceinline__ void cxrr2(float2 (&a)[K])
{
#pragma unroll
    for (int k = 0; k < K; k++)
        if ((k & CM) && !(k & TM)) {
            float2 t = a[k]; a[k] = a[k | TM]; a[k | TM] = t;
        }
}

template <int K, int TM>        // CX, ctrl = COMPONENT bit, packed target
__device__ __forceinline__ void cxcr2(float2 (&a)[K])
{
#pragma unroll
    for (int k = 0; k < K; k++)
        if ((k & TM) == 0) {    // swap y-components (ctrl=1 amps) across TM
            float t = a[k].y; a[k].y = a[k | TM].y; a[k | TM].y = t;
        }
}

// ---------------------------------------------------------------------------
// prep: one-hot decode (coalesced), H0, theta trig tables, zero M
// ---------------------------------------------------------------------------
__global__ __launch_bounds__(256) void prep_kernel(
    const float* __restrict__ X, const float* __restrict__ Ri,
    const float* __restrict__ Ro, const float* __restrict__ W,
    const float* __restrict__ th_e, const float* __restrict__ th_n,
    int* __restrict__ snd, int* __restrict__ rcv, float* __restrict__ H0,
    float* __restrict__ cte, float* __restrict__ ste,
    float* __restrict__ ctn, float* __restrict__ stn,
    float* __restrict__ M)
{
    int idx = blockIdx.x * blockDim.x + threadIdx.x;
    if (idx < N_NODES * N_EDGES) {
        int n = idx / N_EDGES, e = idx - n * N_EDGES;
        if (Ro[idx] > 0.5f) snd[e] = n;
        if (Ri[idx] > 0.5f) rcv[e] = n;
    }
    if (idx < N_NODES) {
        int n = idx;
        float x0 = X[n * 3 + 0], x1 = X[n * 3 + 1], x2 = X[n * 3 + 2];
        float t0 = x0 * W[0] + x1 * W[2] + x2 * W[4];
        float t1 = x0 * W[1] + x1 * W[3] + x2 * W[5];
        const float TP = 6.2831853071795864769f;
        H0[n * 5 + 0] = TP / (1.f + __expf(-t0));
        H0[n * 5 + 1] = TP / (1.f + __expf(-t1));
        H0[n * 5 + 2] = x0;
        H0[n * 5 + 3] = x1;
        H0[n * 5 + 4] = x2;
    } else if (idx >= 512 && idx < 512 + 19) {
        int j = idx - 512;
        float h = 0.5f * th_e[j];
        cte[j] = __cosf(h); ste[j] = __sinf(h);
    } else if (idx >= 576 && idx < 576 + 31) {
        int j = idx - 576;
        float h = 0.5f * th_n[j];
        ctn[j] = __cosf(h); stn[j] = __sinf(h);
    } else if (idx >= 1024 && idx < 1024 + N_NODES * 10) {
        M[idx - 1024] = 0.f;
    }
}

// ---------------------------------------------------------------------------
// edge circuit (first-RY absorbed, r7-verified order), float2-packed.
// 4 edges/block (4 waves). 8 float2/lane.
//   lane bits: m1=w1, m2=w0, m4=w3, m8=w5, m16=w6, m32=w8
//   packed-index bits: m1=w7, m2=w2, m4=w4;  component = w9 (least-gated)
// do_agg: fused aggregation atomics (skipped on the final pass).
// ---------------------------------------------------------------------------
__global__ __launch_bounds__(256) void edge_kernel(
    const float* __restrict__ H, const int* __restrict__ snd, const int* __restrict__ rcv,
    const float* __restrict__ cte, const float* __restrict__ ste,
    const float* __restrict__ th_e,
    float* __restrict__ out, float* __restrict__ M, int do_agg)
{
    const int e = blockIdx.x * 4 + (threadIdx.x >> 6);
    const int lane = threadIdx.x & 63;
    const int se = snd[e], re = rcv[e];

    float f[10];
#pragma unroll
    for (int k = 0; k < 5; k++) { f[k] = H[se * 5 + k]; f[5 + k] = H[re * 5 + k]; }

    float cw[10], sw[10];
#pragma unroll
    for (int w = 0; w < 10; w++) {
        float h = 0.5f * (f[w] + th_e[w]);      // absorbed first RY
        sw[w] = __sinf(h);
        cw[w] = __cosf(h);
    }

    float pl = 1.f;
    pl *= (lane & 1)  ? sw[1] : cw[1];
    pl *= (lane & 2)  ? sw[0] : cw[0];
    pl *= (lane & 4)  ? sw[3] : cw[3];
    pl *= (lane & 8)  ? sw[5] : cw[5];
    pl *= (lane & 16) ? sw[6] : cw[6];
    pl *= (lane & 32) ? sw[8] : cw[8];
    float2 a[8];
#pragma unroll
    for (int k = 0; k < 8; k++) {
        float p = pl;
        p *= (k & 1) ? sw[7] : cw[7];
        p *= (k & 2) ? sw[2] : cw[2];
        p *= (k & 4) ? sw[4] : cw[4];
        a[k].x = p * cw[9];
        a[k].y = p * sw[9];
    }

    cxl2<8, 1>(a, (lane & 2) != 0);              // cx(0,1)  tgt w1 (DPP)
    cxr2<8, 2>(a, (lane & 4) != 0);              // cx(3,2)
    cxr2<8, 4>(a, (lane & 8) != 0);              // cx(5,4)
    cxr2<8, 1>(a, (lane & 16) != 0);             // cx(6,7)
    cxc2<8>(a, (lane & 32) != 0);                // cx(8,9)  tgt w9 = component
    ryl2<8, 1>(a, lane, cte[10], ste[10]);       // ry(10,w1) (DPP)
    ryr2<8, 2>(a, cte[11], ste[11]);             // ry(11,w2)
    cxr2<8, 2>(a, (lane & 1) != 0);              // cx(1,2)
    ryr2<8, 1>(a, cte[12], ste[12]);             // ry(12,w7)
    ryc2<8>(a, cte[13], ste[13]);                // ry(13,w9) component
    cxcr2<8, 1>(a);                              // cx(9,7)  ctrl=component
    ryr2<8, 2>(a, cte[14], ste[14]);             // ry(14,w2)
    ryr2<8, 4>(a, cte[15], ste[15]);             // ry(15,w4)
    cxrr2<8, 2, 4>(a);                           // cx(2,4)
    ryr2<8, 4>(a, cte[16], ste[16]);             // ry(16,w4)
    ryr2<8, 1>(a, cte[17], ste[17]);             // ry(17,w7)
    cxrr2<8, 4, 1>(a);                           // cx(4,7)
    ryr2<8, 1>(a, cte[18], ste[18]);             // ry(18,w7)

    // expz wire7 -> packed-index bit m1
    float z = 0.f;
#pragma unroll
    for (int k = 0; k < 8; k++) {
        float v = a[k].x * a[k].x + a[k].y * a[k].y;
        z += (k & 1) ? -v : v;
    }
#pragma unroll
    for (int o = 32; o > 0; o >>= 1) z += __shfl_xor(z, o, 64);   // all lanes get z
    float ev = 0.5f * (1.f - z);

    if (lane == 0) out[e] = ev;
    if (do_agg) {
        if (lane < 5)       atomicAdd(&M[re * 10 + lane], ev * f[lane]);
        else if (lane < 10) atomicAdd(&M[se * 10 + lane], ev * f[lane]);
    }
}

// ---------------------------------------------------------------------------
// node circuit (first-RY absorbed + CX^2 cancelled, r7-verified order),
// float2-packed. 32768 amps across 1024 threads, 16 float2/thread.
//   packed-index bits m1,2,4,8 = wires {10, 5, 2, 13}; component = w14
//   lane bits m1..m32 = wires {9, 1, 0, 6, 8, 12}
//   wave bits b0..b3 = wires {3, 4, 7, 11} (control-only)
// Block re-zeros its own M row after reading (next edge pass re-accumulates).
// ---------------------------------------------------------------------------
__global__ __launch_bounds__(1024, 4) void node_kernel(
    const float* __restrict__ H, float* __restrict__ M,
    const float* __restrict__ ctn, const float* __restrict__ stn,
    const float* __restrict__ th_n,
    const float* __restrict__ X, float* __restrict__ Hout)
{
    const int n = blockIdx.x;
    const int tid = threadIdx.x;
    const int lane = tid & 63;
    const int wv = tid >> 6;

    __shared__ float cw[15], sw[15];            // indexed by PHYSICAL bit
    __shared__ float red[32];

    if (tid < 15) {
        const int wire_of_pb[15] = {10, 5, 2, 13, 14, 9, 1, 0, 6, 8, 12, 3, 4, 7, 11};
        int w_ = wire_of_pb[tid];
        float ang = ((w_ < 10) ? M[n * 10 + w_] : H[n * 5 + (w_ - 10)]) + th_n[w_];
        float h = 0.5f * ang;                   // absorbed first RY
        sw[tid] = __sinf(h);
        cw[tid] = __cosf(h);
    }
    __syncthreads();
    if (tid < 10) M[n * 10 + tid] = 0.f;        // re-zero own row for next edge pass

    float pw = 1.f;
#pragma unroll
    for (int k = 0; k < 6; k++) pw *= ((lane >> k) & 1) ? sw[5 + k] : cw[5 + k];
#pragma unroll
    for (int k = 0; k < 4; k++) pw *= ((wv >> k) & 1) ? sw[11 + k] : cw[11 + k];
    float2 a[16];
#pragma unroll
    for (int k = 0; k < 16; k++) {
        float p = pw;
#pragma unroll
        for (int j = 0; j < 4; j++) p *= ((k >> j) & 1) ? sw[j] : cw[j];
        a[k].x = p * cw[4];                     // component = w14
        a[k].y = p * sw[4];
    }

    cxl2<16, 2>(a, (lane & 4) != 0);             // cx(0,1)   tgt w1 (DPP)
    cxr2<16, 4>(a, (wv & 1) != 0);               // cx(3,2)
    cxr2<16, 2>(a, (wv & 2) != 0);               // cx(4,5)
    cxl2<16, 8>(a, (wv & 4) != 0);               // cx(7,6)   tgt w6 (DPP)
    cxr2<16, 1>(a, (wv & 8) != 0);               // cx(11,10)
    ryl2<16, 2>(a, lane, ctn[15], stn[15]);      // ry(15,w1) (DPP)
    ryr2<16, 4>(a, ctn[16], stn[16]);            // ry(16,w2)
    cxr2<16, 4>(a, (lane & 2) != 0);             // cx(1,2)
    ryr2<16, 2>(a, ctn[14], stn[14]);            // ry(14,w5)
    ryl2<16, 8>(a, lane, ctn[15], stn[15]);      // ry(15,w6) (DPP)
    cxr2<16, 2>(a, (lane & 8) != 0);             // cx(6,5)
    ryl2<16, 1>(a, lane, ctn[16], stn[16]);      // ry(16,w9) (DPP)
    ryr2<16, 1>(a, ctn[17], stn[17]);            // ry(17,w10)
    ryr2<16, 8>(a, ctn[18], stn[18]);            // ry(18,w13)
    ryc2<16>(a, ctn[19], stn[19]);               // ry(19,w14) component
    ryr2<16, 4>(a, ctn[19], stn[19]);            // ry(19,w2)
    ryr2<16, 2>(a, ctn[20], stn[20]);            // ry(20,w5)
    cxrr2<16, 4, 2>(a);                          // cx(2,5)
    ryr2<16, 1>(a, ctn[21], stn[21]);            // ry(21,w10)
    ryr2<16, 8>(a, ctn[22], stn[22]);            // ry(22,w13)
    cxrr2<16, 8, 1>(a);                          // cx(13,10)
    ryr2<16, 2>(a, ctn[23], stn[23]);            // ry(23,w5)
    ryr2<16, 1>(a, ctn[24], stn[24]);            // ry(24,w10)
    ryl2<16, 4>(a, lane, ctn[25], stn[25]);      // ry(25,w0) (the one shfl gate)
    ryr2<16, 2>(a, ctn[26], stn[26]);            // ry(26,w5)
    cxr2<16, 2>(a, (lane & 4) != 0);             // cx(0,5)
    ryr2<16, 1>(a, ctn[27], stn[27]);            // ry(27,w10)
    ryc2<16>(a, ctn[28], stn[28]);               // ry(28,w14) component
    cxcr2<16, 1>(a);                             // cx(14,10) ctrl=component
    ryr2<16, 2>(a, ctn[29], stn[29]);            // ry(29,w5)
    ryr2<16, 1>(a, ctn[30], stn[30]);            // ry(30,w10)

    // expz: wire5 -> packed m2, wire10 -> packed m1
    float z5 = 0.f, z10 = 0.f;
#pragma unroll
    for (int k = 0; k < 16; k++) {
        float v = a[k].x * a[k].x + a[k].y * a[k].y;
        z5  += (k & 2) ? -v : v;
        z10 += (k & 1) ? -v : v;
    }
#pragma unroll
    for (int o = 32; o > 0; o >>= 1) {
        z5  += __shfl_xor(z5, o, 64);
        z10 += __shfl_xor(z10, o, 64);
    }
    if (lane == 0) { red[wv] = z5; red[16 + wv] = z10; }
    __syncthreads();
    if (tid == 0) {
        float a5 = 0.f, a10 = 0.f;
#pragma unroll
        for (int k = 0; k < 16; k++) { a5 += red[k]; a10 += red[16 + k]; }
        const float PI_ = 3.14159265358979323846f;
        Hout[n * 5 + 0] = PI_ * (1.f - a5);
        Hout[n * 5 + 1] = PI_ * (1.f - a10);
        Hout[n * 5 + 2] = X[n * 3 + 0];
        Hout[n * 5 + 3] = X[n * 3 + 1];
        Hout[n * 5 + 4] = X[n * 3 + 2];
    }
}

// ---------------------------------------------------------------------------
extern "C" void kernel_launch(void* const* d_in, const int* in_sizes, int n_in,
                              void* d_out, int out_size, void* d_ws, size_t ws_size,
                              hipStream_t stream)
{
    const float* X    = (const float*)d_in[0];
    const float* Ri   = (const float*)d_in[1];
    const float* Ro   = (const float*)d_in[2];
    const float* W    = (const float*)d_in[3];
    const float* th_e = (const float*)d_in[4];
    const float* th_n = (const float*)d_in[5];
    float* out = (float*)d_out;

    float* Ha  = (float*)d_ws;              // 1920
    float* Hb  = Ha + N_NODES * 5;          // 1920
    float* ev  = Hb + N_NODES * 5;          // 1280
    int*   snd = (int*)(ev + N_EDGES);      // 1280
    int*   rcv = snd + N_EDGES;             // 1280
    float* M   = (float*)(rcv + N_EDGES);   // 3840
    float* cte = M + N_NODES * 10;          // 19
    float* ste = cte + 19;                  // 19
    float* ctn = ste + 19;                  // 31
    float* stn = ctn + 31;                  // 31

    prep_kernel<<<(N_NODES * N_EDGES + 255) / 256, 256, 0, stream>>>(
        X, Ri, Ro, W, th_e, th_n, snd, rcv, Ha, cte, ste, ctn, stn, M);

    edge_kernel<<<N_EDGES / 4, 256, 0, stream>>>(Ha, snd, rcv, cte, ste, th_e, ev, M, 1);
    node_kernel<<<N_NODES, 1024, 0, stream>>>(Ha, M, ctn, stn, th_n, X, Hb);

    edge_kernel<<<N_EDGES / 4, 256, 0, stream>>>(Hb, snd, rcv, cte, ste, th_e, ev, M, 1);
    node_kernel<<<N_NODES, 1024, 0, stream>>>(Hb, M, ctn, stn, th_n, X, Ha);

    edge_kernel<<<N_EDGES / 4, 256, 0, stream>>>(Ha, snd, rcv, cte, ste, th_e, out, M, 0);
}

// Round 11
// 68.023 us; speedup vs baseline: 6.2705x; 1.1554x over previous
//
#include <hip/hip_runtime.h>
#include <math.h>

#define N_NODES 384
#define N_EDGES 1280

// ---------------------------------------------------------------------------
// Lane-exchange: DPP for xor masks 1,2,8 (VALU pipe, verified r6-r8):
//   xor1 = quad_perm [1,0,3,2]; xor2 = quad_perm [2,3,0,1]; xor8 = row_ror:8.
// Masks 4,16,32 -> __shfl_xor. Permlane swaps: BANNED (r3/r4 failures).
// ---------------------------------------------------------------------------
template <int M>
__device__ __forceinline__ float lxor_f(float x)
{
    if constexpr (M == 1) {
        return __builtin_bit_cast(float, __builtin_amdgcn_mov_dpp(
            __builtin_bit_cast(int, x), 0xB1, 0xF, 0xF, true));
    } else if constexpr (M == 2) {
        return __builtin_bit_cast(float, __builtin_amdgcn_mov_dpp(
            __builtin_bit_cast(int, x), 0x4E, 0xF, 0xF, true));
    } else if constexpr (M == 8) {
        return __builtin_bit_cast(float, __builtin_amdgcn_mov_dpp(
            __builtin_bit_cast(int, x), 0x128, 0xF, 0xF, true));
    } else {
        return __shfl_xor(x, M, 64);        // masks 4, 16, 32
    }
}

// ---------------------------------------------------------------------------
// float2-packed gate helpers (r8-verified algebra).
// ---------------------------------------------------------------------------
template <int K, int M>         // RY on a packed-index bit (elementwise f2)
__device__ __forceinline__ void ryr2(float2 (&a)[K], float c_, float s_)
{
#pragma unroll
    for (int k = 0; k < K; k++)
        if ((k & M) == 0) {
            float2 u = a[k], v = a[k | M];
            a[k].x     = c_ * u.x - s_ * v.x;
            a[k].y     = c_ * u.y - s_ * v.y;
            a[k | M].x = s_ * u.x + c_ * v.x;
            a[k | M].y = s_ * u.y + c_ * v.y;
        }
}

template <int K>                // RY on the component bit (x/y rotate)
__device__ __forceinline__ void ryc2(float2 (&a)[K], float c_, float s_)
{
#pragma unroll
    for (int k = 0; k < K; k++) {
        float x = a[k].x, y = a[k].y;
        a[k].x = c_ * x - s_ * y;
        a[k].y = s_ * x + c_ * y;
    }
}

template <int K, int LM>        // RY on a lane bit
__device__ __forceinline__ void ryl2(float2 (&a)[K], int lane, float c_, float s_)
{
    const float ss = (lane & LM) ? s_ : -s_;
#pragma unroll
    for (int k = 0; k < K; k++) {
        float ox = lxor_f<LM>(a[k].x);
        float oy = lxor_f<LM>(a[k].y);
        a[k].x = fmaf(ss, ox, c_ * a[k].x);
        a[k].y = fmaf(ss, oy, c_ * a[k].y);
    }
}

template <int K, int TM>        // CX, bool ctrl, lane-bit target
__device__ __forceinline__ void cxl2(float2 (&a)[K], bool ctrl)
{
#pragma unroll
    for (int k = 0; k < K; k++) {
        float ox = lxor_f<TM>(a[k].x);
        float oy = lxor_f<TM>(a[k].y);
        a[k].x = ctrl ? ox : a[k].x;
        a[k].y = ctrl ? oy : a[k].y;
    }
}

template <int K, int TM>        // CX, bool ctrl, packed-index target
__device__ __forceinline__ void cxr2(float2 (&a)[K], bool ctrl)
{
#pragma unroll
    for (int k = 0; k < K; k++)
        if ((k & TM) == 0) {
            float2 u = a[k], v = a[k | TM];
            a[k].x      = ctrl ? v.x : u.x;
            a[k].y      = ctrl ? v.y : u.y;
            a[k | TM].x = ctrl ? u.x : v.x;
            a[k | TM].y = ctrl ? u.y : v.y;
        }
}

template <int K>                // CX, bool ctrl, COMPONENT target (x<->y)
__device__ __forceinline__ void cxc2(float2 (&a)[K], bool ctrl)
{
#pragma unroll
    for (int k = 0; k < K; k++) {
        float x = a[k].x, y = a[k].y;
        a[k].x = ctrl ? y : x;
        a[k].y = ctrl ? x : y;
    }
}

template <int K, int CM, int TM>  // CX, packed ctrl + packed target (rename)
__device__ __forceinline__ void cxrr2(float2 (&a)[K])
{
#pragma unroll
    for (int k = 0; k < K; k++)
        if ((k & CM) && !(k & TM)) {
            float2 t = a[k]; a[k] = a[k | TM]; a[k | TM] = t;
        }
}

template <int K, int TM>        // CX, ctrl = COMPONENT bit, packed target
__device__ __forceinline__ void cxcr2(float2 (&a)[K])
{
#pragma unroll
    for (int k = 0; k < K; k++)
        if ((k & TM) == 0) {    // swap y-components (ctrl=1 amps) across TM
            float t = a[k].y; a[k].y = a[k | TM].y; a[k | TM].y = t;
        }
}

// ---------------------------------------------------------------------------
// prep: one-hot decode (coalesced), H0, theta trig tables, zero M
// ---------------------------------------------------------------------------
__global__ __launch_bounds__(256) void prep_kernel(
    const float* __restrict__ X, const float* __restrict__ Ri,
    const float* __restrict__ Ro, const float* __restrict__ W,
    const float* __restrict__ th_e, const float* __restrict__ th_n,
    int* __restrict__ snd, int* __restrict__ rcv, float* __restrict__ H0,
    float* __restrict__ cte, float* __restrict__ ste,
    float* __restrict__ ctn, float* __restrict__ stn,
    float* __restrict__ M)
{
    int idx = blockIdx.x * blockDim.x + threadIdx.x;
    if (idx < N_NODES * N_EDGES) {
        int n = idx / N_EDGES, e = idx - n * N_EDGES;
        if (Ro[idx] > 0.5f) snd[e] = n;
        if (Ri[idx] > 0.5f) rcv[e] = n;
    }
    if (idx < N_NODES) {
        int n = idx;
        float x0 = X[n * 3 + 0], x1 = X[n * 3 + 1], x2 = X[n * 3 + 2];
        float t0 = x0 * W[0] + x1 * W[2] + x2 * W[4];
        float t1 = x0 * W[1] + x1 * W[3] + x2 * W[5];
        const float TP = 6.2831853071795864769f;
        H0[n * 5 + 0] = TP / (1.f + __expf(-t0));
        H0[n * 5 + 1] = TP / (1.f + __expf(-t1));
        H0[n * 5 + 2] = x0;
        H0[n * 5 + 3] = x1;
        H0[n * 5 + 4] = x2;
    } else if (idx >= 512 && idx < 512 + 19) {
        int j = idx - 512;
        float h = 0.5f * th_e[j];
        cte[j] = __cosf(h); ste[j] = __sinf(h);
    } else if (idx >= 576 && idx < 576 + 31) {
        int j = idx - 576;
        float h = 0.5f * th_n[j];
        ctn[j] = __cosf(h); stn[j] = __sinf(h);
    } else if (idx >= 1024 && idx < 1024 + N_NODES * 10) {
        M[idx - 1024] = 0.f;
    }
}

// ---------------------------------------------------------------------------
// edge circuit (r8-verified, UNCHANGED). 4 edges/block, 8 float2/lane.
//   lane bits: m1=w1, m2=w0, m4=w3, m8=w5, m16=w6, m32=w8
//   packed-index bits: m1=w7, m2=w2, m4=w4;  component = w9
// ---------------------------------------------------------------------------
__global__ __launch_bounds__(256) void edge_kernel(
    const float* __restrict__ H, const int* __restrict__ snd, const int* __restrict__ rcv,
    const float* __restrict__ cte, const float* __restrict__ ste,
    const float* __restrict__ th_e,
    float* __restrict__ out, float* __restrict__ M, int do_agg)
{
    const int e = blockIdx.x * 4 + (threadIdx.x >> 6);
    const int lane = threadIdx.x & 63;
    const int se = snd[e], re = rcv[e];

    float f[10];
#pragma unroll
    for (int k = 0; k < 5; k++) { f[k] = H[se * 5 + k]; f[5 + k] = H[re * 5 + k]; }

    float cw[10], sw[10];
#pragma unroll
    for (int w = 0; w < 10; w++) {
        float h = 0.5f * (f[w] + th_e[w]);      // absorbed first RY
        sw[w] = __sinf(h);
        cw[w] = __cosf(h);
    }

    float pl = 1.f;
    pl *= (lane & 1)  ? sw[1] : cw[1];
    pl *= (lane & 2)  ? sw[0] : cw[0];
    pl *= (lane & 4)  ? sw[3] : cw[3];
    pl *= (lane & 8)  ? sw[5] : cw[5];
    pl *= (lane & 16) ? sw[6] : cw[6];
    pl *= (lane & 32) ? sw[8] : cw[8];
    float2 a[8];
#pragma unroll
    for (int k = 0; k < 8; k++) {
        float p = pl;
        p *= (k & 1) ? sw[7] : cw[7];
        p *= (k & 2) ? sw[2] : cw[2];
        p *= (k & 4) ? sw[4] : cw[4];
        a[k].x = p * cw[9];
        a[k].y = p * sw[9];
    }

    cxl2<8, 1>(a, (lane & 2) != 0);              // cx(0,1)
    cxr2<8, 2>(a, (lane & 4) != 0);              // cx(3,2)
    cxr2<8, 4>(a, (lane & 8) != 0);              // cx(5,4)
    cxr2<8, 1>(a, (lane & 16) != 0);             // cx(6,7)
    cxc2<8>(a, (lane & 32) != 0);                // cx(8,9)
    ryl2<8, 1>(a, lane, cte[10], ste[10]);       // ry(10,w1)
    ryr2<8, 2>(a, cte[11], ste[11]);             // ry(11,w2)
    cxr2<8, 2>(a, (lane & 1) != 0);              // cx(1,2)
    ryr2<8, 1>(a, cte[12], ste[12]);             // ry(12,w7)
    ryc2<8>(a, cte[13], ste[13]);                // ry(13,w9)
    cxcr2<8, 1>(a);                              // cx(9,7)
    ryr2<8, 2>(a, cte[14], ste[14]);             // ry(14,w2)
    ryr2<8, 4>(a, cte[15], ste[15]);             // ry(15,w4)
    cxrr2<8, 2, 4>(a);                           // cx(2,4)
    ryr2<8, 4>(a, cte[16], ste[16]);             // ry(16,w4)
    ryr2<8, 1>(a, cte[17], ste[17]);             // ry(17,w7)
    cxrr2<8, 4, 1>(a);                           // cx(4,7)
    ryr2<8, 1>(a, cte[18], ste[18]);             // ry(18,w7)

    float z = 0.f;
#pragma unroll
    for (int k = 0; k < 8; k++) {
        float v = a[k].x * a[k].x + a[k].y * a[k].y;
        z += (k & 1) ? -v : v;
    }
#pragma unroll
    for (int o = 32; o > 0; o >>= 1) z += __shfl_xor(z, o, 64);
    float ev = 0.5f * (1.f - z);

    if (lane == 0) out[e] = ev;
    if (do_agg) {
        if (lane < 5)       atomicAdd(&M[re * 10 + lane], ev * f[lane]);
        else if (lane < 10) atomicAdd(&M[se * 10 + lane], ev * f[lane]);
    }
}

// ---------------------------------------------------------------------------
// node circuit = ROUND-8 CHASSIS (passed, 78.6us) with exactly two changes:
//  (1) ry(16,w9) DELETED (lightcone: last gate on unmeasured wire 9)
//  (2) five commuting-RY merges, trig computed in-kernel from th_n:
//      (17+21)w10, (18+22)w13, (19+28)w14, (23+26)w5, (24+27)w10
// Everything else byte-identical to r8 (1024 thr, wave bits, layout).
//   packed m1,2,4,8 = {10, 5, 2, 13}; component = w14
//   lane m1..m32 = {9, 1, 0, 6, 8, 12}; wave b0..b3 = {3, 4, 7, 11}
// ---------------------------------------------------------------------------
__global__ __launch_bounds__(1024, 4) void node_kernel(
    const float* __restrict__ H, float* __restrict__ M,
    const float* __restrict__ ctn, const float* __restrict__ stn,
    const float* __restrict__ th_n,
    const float* __restrict__ X, float* __restrict__ Hout)
{
    const int n = blockIdx.x;
    const int tid = threadIdx.x;
    const int lane = tid & 63;
    const int wv = tid >> 6;

    __shared__ float cw[15], sw[15];            // indexed by PHYSICAL bit
    __shared__ float red[32];

    if (tid < 15) {
        const int wire_of_pb[15] = {10, 5, 2, 13, 14, 9, 1, 0, 6, 8, 12, 3, 4, 7, 11};
        int w_ = wire_of_pb[tid];
        float ang = ((w_ < 10) ? M[n * 10 + w_] : H[n * 5 + (w_ - 10)]) + th_n[w_];
        float h = 0.5f * ang;                   // absorbed first RY
        sw[tid] = __sinf(h);
        cw[tid] = __cosf(h);
    }
    __syncthreads();
    if (tid < 10) M[n * 10 + tid] = 0.f;        // re-zero own row for next edge pass

    // merged-gate trig (the r11 bisect delta), verified __sinf/__cosf only
    float h1721 = 0.5f * (th_n[17] + th_n[21]);
    float h1822 = 0.5f * (th_n[18] + th_n[22]);
    float h1928 = 0.5f * (th_n[19] + th_n[28]);
    float h2326 = 0.5f * (th_n[23] + th_n[26]);
    float h2427 = 0.5f * (th_n[24] + th_n[27]);
    float ms1721 = __sinf(h1721), mc1721 = __cosf(h1721);
    float ms1822 = __sinf(h1822), mc1822 = __cosf(h1822);
    float ms1928 = __sinf(h1928), mc1928 = __cosf(h1928);
    float ms2326 = __sinf(h2326), mc2326 = __cosf(h2326);
    float ms2427 = __sinf(h2427), mc2427 = __cosf(h2427);

    float pw = 1.f;
#pragma unroll
    for (int k = 0; k < 6; k++) pw *= ((lane >> k) & 1) ? sw[5 + k] : cw[5 + k];
#pragma unroll
    for (int k = 0; k < 4; k++) pw *= ((wv >> k) & 1) ? sw[11 + k] : cw[11 + k];
    float2 a[16];
#pragma unroll
    for (int k = 0; k < 16; k++) {
        float p = pw;
#pragma unroll
        for (int j = 0; j < 4; j++) p *= ((k >> j) & 1) ? sw[j] : cw[j];
        a[k].x = p * cw[4];                     // component = w14
        a[k].y = p * sw[4];
    }

    cxl2<16, 2>(a, (lane & 4) != 0);             // cx(0,1)   tgt w1 (DPP)
    cxr2<16, 4>(a, (wv & 1) != 0);               // cx(3,2)
    cxr2<16, 2>(a, (wv & 2) != 0);               // cx(4,5)
    cxl2<16, 8>(a, (wv & 4) != 0);               // cx(7,6)   tgt w6 (DPP)
    cxr2<16, 1>(a, (wv & 8) != 0);               // cx(11,10)
    ryl2<16, 2>(a, lane, ctn[15], stn[15]);      // ry(15,w1) (DPP)
    ryr2<16, 4>(a, ctn[16], stn[16]);            // ry(16,w2)
    cxr2<16, 4>(a, (lane & 2) != 0);             // cx(1,2)
    ryr2<16, 2>(a, ctn[14], stn[14]);            // ry(14,w5)
    ryl2<16, 8>(a, lane, ctn[15], stn[15]);      // ry(15,w6) (DPP)
    cxr2<16, 2>(a, (lane & 8) != 0);             // cx(6,5)
    /* ry(16,w9) DELETED — lightcone drop */
    ryr2<16, 1>(a, mc1721, ms1721);              // ry(17+21,w10)  MERGED
    ryr2<16, 8>(a, mc1822, ms1822);              // ry(18+22,w13)  MERGED
    ryc2<16>(a, mc1928, ms1928);                 // ry(19+28,w14)  MERGED
    ryr2<16, 4>(a, ctn[19], stn[19]);            // ry(19,w2)
    ryr2<16, 2>(a, ctn[20], stn[20]);            // ry(20,w5)
    cxrr2<16, 4, 2>(a);                          // cx(2,5)
    cxrr2<16, 8, 1>(a);                          // cx(13,10)
    ryr2<16, 2>(a, mc2326, ms2326);              // ry(23+26,w5)   MERGED
    ryr2<16, 1>(a, mc2427, ms2427);              // ry(24+27,w10)  MERGED
    ryl2<16, 4>(a, lane, ctn[25], stn[25]);      // ry(25,w0) (shfl mask4)
    cxr2<16, 2>(a, (lane & 4) != 0);             // cx(0,5)
    cxcr2<16, 1>(a);                             // cx(14,10) ctrl=component
    ryr2<16, 2>(a, ctn[29], stn[29]);            // ry(29,w5)
    ryr2<16, 1>(a, ctn[30], stn[30]);            // ry(30,w10)

    // expz: wire5 -> packed m2, wire10 -> packed m1
    float z5 = 0.f, z10 = 0.f;
#pragma unroll
    for (int k = 0; k < 16; k++) {
        float v = a[k].x * a[k].x + a[k].y * a[k].y;
        z5  += (k & 2) ? -v : v;
        z10 += (k & 1) ? -v : v;
    }
#pragma unroll
    for (int o = 32; o > 0; o >>= 1) {
        z5  += __shfl_xor(z5, o, 64);
        z10 += __shfl_xor(z10, o, 64);
    }
    if (lane == 0) { red[wv] = z5; red[16 + wv] = z10; }
    __syncthreads();
    if (tid == 0) {
        float a5 = 0.f, a10 = 0.f;
#pragma unroll
        for (int k = 0; k < 16; k++) { a5 += red[k]; a10 += red[16 + k]; }
        const float PI_ = 3.14159265358979323846f;
        Hout[n * 5 + 0] = PI_ * (1.f - a5);
        Hout[n * 5 + 1] = PI_ * (1.f - a10);
        Hout[n * 5 + 2] = X[n * 3 + 0];
        Hout[n * 5 + 3] = X[n * 3 + 1];
        Hout[n * 5 + 4] = X[n * 3 + 2];
    }
}

// ---------------------------------------------------------------------------
extern "C" void kernel_launch(void* const* d_in, const int* in_sizes, int n_in,
                              void* d_out, int out_size, void* d_ws, size_t ws_size,
                              hipStream_t stream)
{
    const float* X    = (const float*)d_in[0];
    const float* Ri   = (const float*)d_in[1];
    const float* Ro   = (const float*)d_in[2];
    const float* W    = (const float*)d_in[3];
    const float* th_e = (const float*)d_in[4];
    const float* th_n = (const float*)d_in[5];
    float* out = (float*)d_out;

    float* Ha  = (float*)d_ws;              // 1920
    float* Hb  = Ha + N_NODES * 5;          // 1920
    float* ev  = Hb + N_NODES * 5;          // 1280
    int*   snd = (int*)(ev + N_EDGES);      // 1280
    int*   rcv = snd + N_EDGES;             // 1280
    float* M   = (float*)(rcv + N_EDGES);   // 3840
    float* cte = M + N_NODES * 10;          // 19
    float* ste = cte + 19;                  // 19
    float* ctn = ste + 19;                  // 31
    float* stn = ctn + 31;                  // 31

    prep_kernel<<<(N_NODES * N_EDGES + 255) / 256, 256, 0, stream>>>(
        X, Ri, Ro, W, th_e, th_n, snd, rcv, Ha, cte, ste, ctn, stn, M);

    edge_kernel<<<N_EDGES / 4, 256, 0, stream>>>(Ha, snd, rcv, cte, ste, th_e, ev, M, 1);
    node_kernel<<<N_NODES, 1024, 0, stream>>>(Ha, M, ctn, stn, th_n, X, Hb);

    edge_kernel<<<N_EDGES / 4, 256, 0, stream>>>(Hb, snd, rcv, cte, ste, th_e, ev, M, 1);
    node_kernel<<<N_NODES, 1024, 0, stream>>>(Hb, M, ctn, stn, th_n, X, Ha);

    edge_kernel<<<N_EDGES / 4, 256, 0, stream>>>(Ha, snd, rcv, cte, ste, th_e, out, M, 0);
}

// Round 12
// 38.548 us; speedup vs baseline: 11.0651x; 1.7646x over previous
//
#include <hip/hip_runtime.h>
#include <math.h>

#define N_NODES 384
#define N_EDGES 1280

// ---------------------------------------------------------------------------
// Lane-exchange: DPP for xor masks 1,2,8 (VALU pipe, verified r6-r11):
//   xor1 = quad_perm [1,0,3,2]; xor2 = quad_perm [2,3,0,1]; xor8 = row_ror:8.
// Masks 4,16,32 -> __shfl_xor. Permlane swaps: BANNED (r3/r4 failures).
// ---------------------------------------------------------------------------
template <int M>
__device__ __forceinline__ float lxor_f(float x)
{
    if constexpr (M == 1) {
        return __builtin_bit_cast(float, __builtin_amdgcn_mov_dpp(
            __builtin_bit_cast(int, x), 0xB1, 0xF, 0xF, true));
    } else if constexpr (M == 2) {
        return __builtin_bit_cast(float, __builtin_amdgcn_mov_dpp(
            __builtin_bit_cast(int, x), 0x4E, 0xF, 0xF, true));
    } else if constexpr (M == 8) {
        return __builtin_bit_cast(float, __builtin_amdgcn_mov_dpp(
            __builtin_bit_cast(int, x), 0x128, 0xF, 0xF, true));
    } else {
        return __shfl_xor(x, M, 64);        // masks 4, 16, 32
    }
}

// ---------------------------------------------------------------------------
// float2-packed gate helpers (r8/r11-verified algebra).
// ---------------------------------------------------------------------------
template <int K, int M>         // RY on a packed-index bit (elementwise f2)
__device__ __forceinline__ void ryr2(float2 (&a)[K], float c_, float s_)
{
#pragma unroll
    for (int k = 0; k < K; k++)
        if ((k & M) == 0) {
            float2 u = a[k], v = a[k | M];
            a[k].x     = c_ * u.x - s_ * v.x;
            a[k].y     = c_ * u.y - s_ * v.y;
            a[k | M].x = s_ * u.x + c_ * v.x;
            a[k | M].y = s_ * u.y + c_ * v.y;
        }
}

template <int K>                // RY on the component bit (x/y rotate)
__device__ __forceinline__ void ryc2(float2 (&a)[K], float c_, float s_)
{
#pragma unroll
    for (int k = 0; k < K; k++) {
        float x = a[k].x, y = a[k].y;
        a[k].x = c_ * x - s_ * y;
        a[k].y = s_ * x + c_ * y;
    }
}

template <int K, int LM>        // RY on a lane bit
__device__ __forceinline__ void ryl2(float2 (&a)[K], int lane, float c_, float s_)
{
    const float ss = (lane & LM) ? s_ : -s_;
#pragma unroll
    for (int k = 0; k < K; k++) {
        float ox = lxor_f<LM>(a[k].x);
        float oy = lxor_f<LM>(a[k].y);
        a[k].x = fmaf(ss, ox, c_ * a[k].x);
        a[k].y = fmaf(ss, oy, c_ * a[k].y);
    }
}

template <int K, int TM>        // CX, bool ctrl, lane-bit target
__device__ __forceinline__ void cxl2(float2 (&a)[K], bool ctrl)
{
#pragma unroll
    for (int k = 0; k < K; k++) {
        float ox = lxor_f<TM>(a[k].x);
        float oy = lxor_f<TM>(a[k].y);
        a[k].x = ctrl ? ox : a[k].x;
        a[k].y = ctrl ? oy : a[k].y;
    }
}

template <int K, int TM>        // CX, bool ctrl, packed-index target
__device__ __forceinline__ void cxr2(float2 (&a)[K], bool ctrl)
{
#pragma unroll
    for (int k = 0; k < K; k++)
        if ((k & TM) == 0) {
            float2 u = a[k], v = a[k | TM];
            a[k].x      = ctrl ? v.x : u.x;
            a[k].y      = ctrl ? v.y : u.y;
            a[k | TM].x = ctrl ? u.x : v.x;
            a[k | TM].y = ctrl ? u.y : v.y;
        }
}

template <int K>                // CX, bool ctrl, COMPONENT target (x<->y)
__device__ __forceinline__ void cxc2(float2 (&a)[K], bool ctrl)
{
#pragma unroll
    for (int k = 0; k < K; k++) {
        float x = a[k].x, y = a[k].y;
        a[k].x = ctrl ? y : x;
        a[k].y = ctrl ? x : y;
    }
}

template <int K, int CM, int TM>  // CX, packed ctrl + packed target (rename)
__device__ __forceinline__ void cxrr2(float2 (&a)[K])
{
#pragma unroll
    for (int k = 0; k < K; k++)
        if ((k & CM) && !(k & TM)) {
            float2 t = a[k]; a[k] = a[k | TM]; a[k | TM] = t;
        }
}

template <int K, int TM>        // CX, ctrl = COMPONENT bit, packed target
__device__ __forceinline__ void cxcr2(float2 (&a)[K])
{
#pragma unroll
    for (int k = 0; k < K; k++)
        if ((k & TM) == 0) {    // swap y-components (ctrl=1 amps) across TM
            float t = a[k].y; a[k].y = a[k | TM].y; a[k | TM].y = t;
        }
}

// ---------------------------------------------------------------------------
// prep: one-hot decode (coalesced), H0, theta trig tables, zero M
// ---------------------------------------------------------------------------
__global__ __launch_bounds__(256) void prep_kernel(
    const float* __restrict__ X, const float* __restrict__ Ri,
    const float* __restrict__ Ro, const float* __restrict__ W,
    const float* __restrict__ th_e, const float* __restrict__ th_n,
    int* __restrict__ snd, int* __restrict__ rcv, float* __restrict__ H0,
    float* __restrict__ cte, float* __restrict__ ste,
    float* __restrict__ ctn, float* __restrict__ stn,
    float* __restrict__ M)
{
    int idx = blockIdx.x * blockDim.x + threadIdx.x;
    if (idx < N_NODES * N_EDGES) {
        int n = idx / N_EDGES, e = idx - n * N_EDGES;
        if (Ro[idx] > 0.5f) snd[e] = n;
        if (Ri[idx] > 0.5f) rcv[e] = n;
    }
    if (idx < N_NODES) {
        int n = idx;
        float x0 = X[n * 3 + 0], x1 = X[n * 3 + 1], x2 = X[n * 3 + 2];
        float t0 = x0 * W[0] + x1 * W[2] + x2 * W[4];
        float t1 = x0 * W[1] + x1 * W[3] + x2 * W[5];
        const float TP = 6.2831853071795864769f;
        H0[n * 5 + 0] = TP / (1.f + __expf(-t0));
        H0[n * 5 + 1] = TP / (1.f + __expf(-t1));
        H0[n * 5 + 2] = x0;
        H0[n * 5 + 3] = x1;
        H0[n * 5 + 4] = x2;
    } else if (idx >= 512 && idx < 512 + 19) {
        int j = idx - 512;
        float h = 0.5f * th_e[j];
        cte[j] = __cosf(h); ste[j] = __sinf(h);
    } else if (idx >= 576 && idx < 576 + 31) {
        int j = idx - 576;
        float h = 0.5f * th_n[j];
        ctn[j] = __cosf(h); stn[j] = __sinf(h);
    } else if (idx >= 1024 && idx < 1024 + N_NODES * 10) {
        M[idx - 1024] = 0.f;
    }
}

// ---------------------------------------------------------------------------
// edge circuit (r8/r11-verified, UNCHANGED). 4 edges/block, 8 float2/lane.
//   lane bits: m1=w1, m2=w0, m4=w3, m8=w5, m16=w6, m32=w8
//   packed-index bits: m1=w7, m2=w2, m4=w4;  component = w9
// ---------------------------------------------------------------------------
__global__ __launch_bounds__(256) void edge_kernel(
    const float* __restrict__ H, const int* __restrict__ snd, const int* __restrict__ rcv,
    const float* __restrict__ cte, const float* __restrict__ ste,
    const float* __restrict__ th_e,
    float* __restrict__ out, float* __restrict__ M, int do_agg)
{
    const int e = blockIdx.x * 4 + (threadIdx.x >> 6);
    const int lane = threadIdx.x & 63;
    const int se = snd[e], re = rcv[e];

    float f[10];
#pragma unroll
    for (int k = 0; k < 5; k++) { f[k] = H[se * 5 + k]; f[5 + k] = H[re * 5 + k]; }

    float cw[10], sw[10];
#pragma unroll
    for (int w = 0; w < 10; w++) {
        float h = 0.5f * (f[w] + th_e[w]);      // absorbed first RY
        sw[w] = __sinf(h);
        cw[w] = __cosf(h);
    }

    float pl = 1.f;
    pl *= (lane & 1)  ? sw[1] : cw[1];
    pl *= (lane & 2)  ? sw[0] : cw[0];
    pl *= (lane & 4)  ? sw[3] : cw[3];
    pl *= (lane & 8)  ? sw[5] : cw[5];
    pl *= (lane & 16) ? sw[6] : cw[6];
    pl *= (lane & 32) ? sw[8] : cw[8];
    float2 a[8];
#pragma unroll
    for (int k = 0; k < 8; k++) {
        float p = pl;
        p *= (k & 1) ? sw[7] : cw[7];
        p *= (k & 2) ? sw[2] : cw[2];
        p *= (k & 4) ? sw[4] : cw[4];
        a[k].x = p * cw[9];
        a[k].y = p * sw[9];
    }

    cxl2<8, 1>(a, (lane & 2) != 0);              // cx(0,1)
    cxr2<8, 2>(a, (lane & 4) != 0);              // cx(3,2)
    cxr2<8, 4>(a, (lane & 8) != 0);              // cx(5,4)
    cxr2<8, 1>(a, (lane & 16) != 0);             // cx(6,7)
    cxc2<8>(a, (lane & 32) != 0);                // cx(8,9)
    ryl2<8, 1>(a, lane, cte[10], ste[10]);       // ry(10,w1)
    ryr2<8, 2>(a, cte[11], ste[11]);             // ry(11,w2)
    cxr2<8, 2>(a, (lane & 1) != 0);              // cx(1,2)
    ryr2<8, 1>(a, cte[12], ste[12]);             // ry(12,w7)
    ryc2<8>(a, cte[13], ste[13]);                // ry(13,w9)
    cxcr2<8, 1>(a);                              // cx(9,7)
    ryr2<8, 2>(a, cte[14], ste[14]);             // ry(14,w2)
    ryr2<8, 4>(a, cte[15], ste[15]);             // ry(15,w4)
    cxrr2<8, 2, 4>(a);                           // cx(2,4)
    ryr2<8, 4>(a, cte[16], ste[16]);             // ry(16,w4)
    ryr2<8, 1>(a, cte[17], ste[17]);             // ry(17,w7)
    cxrr2<8, 4, 1>(a);                           // cx(4,7)
    ryr2<8, 1>(a, cte[18], ste[18]);             // ry(18,w7)

    float z = 0.f;
#pragma unroll
    for (int k = 0; k < 8; k++) {
        float v = a[k].x * a[k].x + a[k].y * a[k].y;
        z += (k & 1) ? -v : v;
    }
#pragma unroll
    for (int o = 32; o > 0; o >>= 1) z += __shfl_xor(z, o, 64);
    float ev = 0.5f * (1.f - z);

    if (lane == 0) out[e] = ev;
    if (do_agg) {
        if (lane < 5)       atomicAdd(&M[re * 10 + lane], ev * f[lane]);
        else if (lane < 10) atomicAdd(&M[se * 10 + lane], ev * f[lane]);
    }
}

// ---------------------------------------------------------------------------
// node circuit = r11-VERIFIED circuit (merges + lightcone drop, passed 68us)
// remapped to the 12 effective qubits {0,1,2,3,4,5,6,7,10,11,13,14}:
// wires 8,9,12 are gate-free + unmeasured (r11 confirmed) -> dropped.
// ONE WAVE PER NODE: 4096 amps = 64 lanes x 32 float2. Minimal delta vs r11:
//   packed m1,2,4,8 = {w10,w5,w2,w13} (UNCHANGED), packed m16 = w3 (ctrl-only)
//   comp = w14 (UNCHANGED)
//   lane m2=w1, m4=w0, m8=w6 (UNCHANGED); m1=w7, m16=w4, m32=w11 (ctrl-only)
// Only the 4 former wave-ctrl CX lines change; all other gate lines are
// byte-copies of r11. Read->__syncthreads->zero structure kept verbatim
// (the vmcnt-ordering fix r9 lacked).
// ---------------------------------------------------------------------------
__global__ __launch_bounds__(64) void node_kernel(
    const float* __restrict__ H, float* __restrict__ M,
    const float* __restrict__ ctn, const float* __restrict__ stn,
    const float* __restrict__ th_n,
    const float* __restrict__ X, float* __restrict__ Hout)
{
    const int n = blockIdx.x;
    const int tid = threadIdx.x;
    const int lane = tid;                       // one wave

    __shared__ float cw[12], sw[12];            // indexed by PHYSICAL bit

    if (tid < 12) {
        const int wire_of_pb[12] = {10, 5, 2, 13, 3, 14, 7, 1, 0, 6, 4, 11};
        int w_ = wire_of_pb[tid];
        float ang = ((w_ < 10) ? M[n * 10 + w_] : H[n * 5 + (w_ - 10)]) + th_n[w_];
        float h = 0.5f * ang;                   // absorbed first RY
        sw[tid] = __sinf(h);
        cw[tid] = __cosf(h);
    }
    __syncthreads();                            // vmcnt drain: M reads complete
    if (tid < 10) M[n * 10 + tid] = 0.f;        // re-zero own row for next edge pass

    // merged-gate trig (r11-verified values)
    float h1721 = 0.5f * (th_n[17] + th_n[21]);
    float h1822 = 0.5f * (th_n[18] + th_n[22]);
    float h1928 = 0.5f * (th_n[19] + th_n[28]);
    float h2326 = 0.5f * (th_n[23] + th_n[26]);
    float h2427 = 0.5f * (th_n[24] + th_n[27]);
    float ms1721 = __sinf(h1721), mc1721 = __cosf(h1721);
    float ms1822 = __sinf(h1822), mc1822 = __cosf(h1822);
    float ms1928 = __sinf(h1928), mc1928 = __cosf(h1928);
    float ms2326 = __sinf(h2326), mc2326 = __cosf(h2326);
    float ms2427 = __sinf(h2427), mc2427 = __cosf(h2427);

    // product state: lane bits pb6..11 = {w7,w1,w0,w6,w4,w11},
    // packed pb0..4 = {w10,w5,w2,w13,w3}, comp pb5 = w14
    float pw = 1.f;
    pw *= (lane & 1)  ? sw[6]  : cw[6];
    pw *= (lane & 2)  ? sw[7]  : cw[7];
    pw *= (lane & 4)  ? sw[8]  : cw[8];
    pw *= (lane & 8)  ? sw[9]  : cw[9];
    pw *= (lane & 16) ? sw[10] : cw[10];
    pw *= (lane & 32) ? sw[11] : cw[11];
    float2 a[32];
#pragma unroll
    for (int k = 0; k < 32; k++) {
        float p = pw;
        p *= (k & 1)  ? sw[0] : cw[0];
        p *= (k & 2)  ? sw[1] : cw[1];
        p *= (k & 4)  ? sw[2] : cw[2];
        p *= (k & 8)  ? sw[3] : cw[3];
        p *= (k & 16) ? sw[4] : cw[4];
        a[k].x = p * cw[5];                     // component = w14
        a[k].y = p * sw[5];
    }

    cxl2<32, 2>(a, (lane & 4) != 0);             // cx(0,1)   tgt w1 (DPP) [= r11]
    cxrr2<32, 16, 4>(a);                         // cx(3,2)   ctrl w3 pk-m16 [CHANGED]
    cxr2<32, 2>(a, (lane & 16) != 0);            // cx(4,5)   ctrl w4 m16   [CHANGED]
    cxl2<32, 8>(a, (lane & 1) != 0);             // cx(7,6)   ctrl w7 m1    [CHANGED]
    cxr2<32, 1>(a, (lane & 32) != 0);            // cx(11,10) ctrl w11 m32  [CHANGED]
    ryl2<32, 2>(a, lane, ctn[15], stn[15]);      // ry(15,w1) (DPP) [= r11]
    ryr2<32, 4>(a, ctn[16], stn[16]);            // ry(16,w2)       [= r11]
    cxr2<32, 4>(a, (lane & 2) != 0);             // cx(1,2)         [= r11]
    ryr2<32, 2>(a, ctn[14], stn[14]);            // ry(14,w5)       [= r11]
    ryl2<32, 8>(a, lane, ctn[15], stn[15]);      // ry(15,w6) (DPP) [= r11]
    cxr2<32, 2>(a, (lane & 8) != 0);             // cx(6,5)         [= r11]
    ryr2<32, 1>(a, mc1721, ms1721);              // ry(17+21,w10)   [= r11]
    ryr2<32, 8>(a, mc1822, ms1822);              // ry(18+22,w13)   [= r11]
    ryc2<32>(a, mc1928, ms1928);                 // ry(19+28,w14)   [= r11]
    ryr2<32, 4>(a, ctn[19], stn[19]);            // ry(19,w2)       [= r11]
    ryr2<32, 2>(a, ctn[20], stn[20]);            // ry(20,w5)       [= r11]
    cxrr2<32, 4, 2>(a);                          // cx(2,5)         [= r11]
    cxrr2<32, 8, 1>(a);                          // cx(13,10)       [= r11]
    ryr2<32, 2>(a, mc2326, ms2326);              // ry(23+26,w5)    [= r11]
    ryr2<32, 1>(a, mc2427, ms2427);              // ry(24+27,w10)   [= r11]
    ryl2<32, 4>(a, lane, ctn[25], stn[25]);      // ry(25,w0) shfl  [= r11]
    cxr2<32, 2>(a, (lane & 4) != 0);             // cx(0,5)         [= r11]
    cxcr2<32, 1>(a);                             // cx(14,10)       [= r11]
    ryr2<32, 2>(a, ctn[29], stn[29]);            // ry(29,w5)       [= r11]
    ryr2<32, 1>(a, ctn[30], stn[30]);            // ry(30,w10)      [= r11]

    // expz: wire5 -> packed m2, wire10 -> packed m1
    float z5 = 0.f, z10 = 0.f;
#pragma unroll
    for (int k = 0; k < 32; k++) {
        float v = a[k].x * a[k].x + a[k].y * a[k].y;
        z5  += (k & 2) ? -v : v;
        z10 += (k & 1) ? -v : v;
    }
#pragma unroll
    for (int o = 32; o > 0; o >>= 1) {
        z5  += __shfl_xor(z5, o, 64);
        z10 += __shfl_xor(z10, o, 64);
    }
    if (lane == 0) {
        const float PI_ = 3.14159265358979323846f;
        Hout[n * 5 + 0] = PI_ * (1.f - z5);
        Hout[n * 5 + 1] = PI_ * (1.f - z10);
        Hout[n * 5 + 2] = X[n * 3 + 0];
        Hout[n * 5 + 3] = X[n * 3 + 1];
        Hout[n * 5 + 4] = X[n * 3 + 2];
    }
}

// ---------------------------------------------------------------------------
extern "C" void kernel_launch(void* const* d_in, const int* in_sizes, int n_in,
                              void* d_out, int out_size, void* d_ws, size_t ws_size,
                              hipStream_t stream)
{
    const float* X    = (const float*)d_in[0];
    const float* Ri   = (const float*)d_in[1];
    const float* Ro   = (const float*)d_in[2];
    const float* W    = (const float*)d_in[3];
    const float* th_e = (const float*)d_in[4];
    const float* th_n = (const float*)d_in[5];
    float* out = (float*)d_out;

    float* Ha  = (float*)d_ws;              // 1920
    float* Hb  = Ha + N_NODES * 5;          // 1920
    float* ev  = Hb + N_NODES * 5;          // 1280
    int*   snd = (int*)(ev + N_EDGES);      // 1280
    int*   rcv = snd + N_EDGES;             // 1280
    float* M   = (float*)(rcv + N_EDGES);   // 3840
    float* cte = M + N_NODES * 10;          // 19
    float* ste = cte + 19;                  // 19
    float* ctn = ste + 19;                  // 31
    float* stn = ctn + 31;                  // 31

    prep_kernel<<<(N_NODES * N_EDGES + 255) / 256, 256, 0, stream>>>(
        X, Ri, Ro, W, th_e, th_n, snd, rcv, Ha, cte, ste, ctn, stn, M);

    edge_kernel<<<N_EDGES / 4, 256, 0, stream>>>(Ha, snd, rcv, cte, ste, th_e, ev, M, 1);
    node_kernel<<<N_NODES, 64, 0, stream>>>(Ha, M, ctn, stn, th_n, X, Hb);

    edge_kernel<<<N_EDGES / 4, 256, 0, stream>>>(Hb, snd, rcv, cte, ste, th_e, ev, M, 1);
    node_kernel<<<N_NODES, 64, 0, stream>>>(Hb, M, ctn, stn, th_n, X, Ha);

    edge_kernel<<<N_EDGES / 4, 256, 0, stream>>>(Ha, snd, rcv, cte, ste, th_e, out, M, 0);
}